// Round 1
// baseline (686.212 us; speedup 1.0000x reference)
//
#include <hip/hip_runtime.h>
#include <math.h>

#define NEG_SLOPE 0.2f

__device__ __forceinline__ float lrelu(float x) { return x > 0.f ? x : NEG_SLOPE * x; }

// ---------------- CSR build ----------------
__global__ void k_count(const int* __restrict__ ei, int* __restrict__ cnt, int E, int n) {
    int e = blockIdx.x * 256 + threadIdx.x;
    int E2 = E + n;
    if (e >= E2) return;
    int d = (e < E) ? ei[E + e] : (e - E);
    atomicAdd(&cnt[d], 1);
}

__global__ __launch_bounds__(1024) void k_scan1(const int* __restrict__ cnt, int* __restrict__ ptr,
                                                int* __restrict__ bsum, int n) {
    int tid = threadIdx.x;
    int i = blockIdx.x * 1024 + tid;
    int v = (i < n) ? cnt[i] : 0;
    int lane = tid & 63, wid = tid >> 6;
    int s = v;
    #pragma unroll
    for (int off = 1; off < 64; off <<= 1) {
        int t = __shfl_up(s, off);
        if (lane >= off) s += t;
    }
    __shared__ int wsum[16];
    if (lane == 63) wsum[wid] = s;
    __syncthreads();
    if (wid == 0) {
        int ws_ = (lane < 16) ? wsum[lane] : 0;
        #pragma unroll
        for (int off = 1; off < 16; off <<= 1) {
            int t = __shfl_up(ws_, off);
            if (lane >= off) ws_ += t;
        }
        if (lane < 16) wsum[lane] = ws_;
    }
    __syncthreads();
    if (wid > 0) s += wsum[wid - 1];
    if (i < n) ptr[i + 1] = s;
    if (tid == 1023) bsum[blockIdx.x] = s;
}

__global__ void k_scan2(int* __restrict__ bsum, int B) {
    int lane = threadIdx.x;  // 64 threads, B <= 64
    int v = (lane < B) ? bsum[lane] : 0;
    int s = v;
    #pragma unroll
    for (int off = 1; off < 64; off <<= 1) {
        int t = __shfl_up(s, off);
        if (lane >= off) s += t;
    }
    if (lane < B) bsum[lane] = s - v;  // exclusive carry
}

__global__ void k_scan3(const int* __restrict__ cnt, int* __restrict__ ptr,
                        const int* __restrict__ bsum, int* __restrict__ fill, int n) {
    int i = blockIdx.x * 256 + threadIdx.x;
    if (i >= n) return;
    int val = ptr[i + 1] + bsum[i >> 10];
    ptr[i + 1] = val;
    fill[i] = val - cnt[i];  // exclusive prefix = row start
    if (i == 0) ptr[0] = 0;
}

__global__ void k_scatter(const int* __restrict__ ei, int* __restrict__ fill,
                          int* __restrict__ csr, int E, int n) {
    int e = blockIdx.x * 256 + threadIdx.x;
    int E2 = E + n;
    if (e >= E2) return;
    int s, d;
    if (e < E) { s = ei[e]; d = ei[E + e]; } else { s = d = e - E; }
    int pos = atomicAdd(&fill[d], 1);
    csr[pos] = s;
}

// ---------------- GEMM: H = X @ W, K=128, Ncols=128 ----------------
__global__ __launch_bounds__(256) void k_gemm128(const float* __restrict__ X, const float* __restrict__ W,
                                                 float* __restrict__ Hout, int n) {
    __shared__ float Wl[64 * 128];  // 32 KB: K-half of W
    __shared__ float Xl[64 * 32];   // 8 KB: 32 rows x 64 k, swizzled
    int tid = threadIdx.x;
    int row0 = blockIdx.x * 32;
    int cg = tid & 31, ng = tid >> 5;
    int c0 = cg * 4, r0 = ng * 4;
    float acc[4][4] = {{0.f}};
    for (int kb = 0; kb < 128; kb += 64) {
        const float4* Wg = (const float4*)(W + (size_t)kb * 128);
        float4* Wl4 = (float4*)Wl;
        #pragma unroll
        for (int j = 0; j < 8; ++j) Wl4[tid + j * 256] = Wg[tid + j * 256];
        #pragma unroll
        for (int j = 0; j < 2; ++j) {
            int idx = tid + j * 256;  // 512 float4
            int r = idx >> 4;         // 0..31
            int k4 = idx & 15;        // 0..15
            float4 v = make_float4(0.f, 0.f, 0.f, 0.f);
            if (row0 + r < n) v = ((const float4*)(X + (size_t)(row0 + r) * 128 + kb))[k4];
            int k = k4 * 4;
            Xl[(k + 0) * 32 + (r ^ ((k + 0) & 31))] = v.x;
            Xl[(k + 1) * 32 + (r ^ ((k + 1) & 31))] = v.y;
            Xl[(k + 2) * 32 + (r ^ ((k + 2) & 31))] = v.z;
            Xl[(k + 3) * 32 + (r ^ ((k + 3) & 31))] = v.w;
        }
        __syncthreads();
        #pragma unroll
        for (int k = 0; k < 64; ++k) {
            float4 wv = *(const float4*)&Wl[k * 128 + c0];
            float x0 = Xl[k * 32 + ((r0 + 0) ^ (k & 31))];
            float x1 = Xl[k * 32 + ((r0 + 1) ^ (k & 31))];
            float x2 = Xl[k * 32 + ((r0 + 2) ^ (k & 31))];
            float x3 = Xl[k * 32 + ((r0 + 3) ^ (k & 31))];
            acc[0][0] += x0 * wv.x; acc[0][1] += x0 * wv.y; acc[0][2] += x0 * wv.z; acc[0][3] += x0 * wv.w;
            acc[1][0] += x1 * wv.x; acc[1][1] += x1 * wv.y; acc[1][2] += x1 * wv.z; acc[1][3] += x1 * wv.w;
            acc[2][0] += x2 * wv.x; acc[2][1] += x2 * wv.y; acc[2][2] += x2 * wv.z; acc[2][3] += x2 * wv.w;
            acc[3][0] += x3 * wv.x; acc[3][1] += x3 * wv.y; acc[3][2] += x3 * wv.z; acc[3][3] += x3 * wv.w;
        }
        __syncthreads();
    }
    #pragma unroll
    for (int i = 0; i < 4; ++i) {
        int r = row0 + r0 + i;
        if (r < n)
            *(float4*)&Hout[(size_t)r * 128 + c0] =
                make_float4(acc[i][0], acc[i][1], acc[i][2], acc[i][3]);
    }
}

// ---------------- attention scores: es/ed [N,4] ----------------
__global__ void k_scores(const float* __restrict__ H, const float* __restrict__ as_,
                         const float* __restrict__ ad_, float* __restrict__ es,
                         float* __restrict__ ed, int n) {
    int i = blockIdx.x * 256 + threadIdx.x;  // over n*4
    if (i >= n * 4) return;
    int nd = i >> 2, h = i & 3;
    const float4* hp = (const float4*)(H + (size_t)nd * 128 + h * 32);
    const float4* sp = (const float4*)(as_ + h * 32);
    const float4* dp = (const float4*)(ad_ + h * 32);
    float s = 0.f, d = 0.f;
    #pragma unroll
    for (int j = 0; j < 8; ++j) {
        float4 hv = hp[j], sv = sp[j], dv = dp[j];
        s += hv.x * sv.x + hv.y * sv.y + hv.z * sv.z + hv.w * sv.w;
        d += hv.x * dv.x + hv.y * dv.y + hv.z * dv.z + hv.w * dv.w;
    }
    es[i] = s;
    ed[i] = d;
}

// ---------------- per-node GAT softmax + aggregate (H=4, C=32) ----------------
__global__ __launch_bounds__(128) void k_node_gat(
    const float* __restrict__ Hf, const float* __restrict__ es, const float* __restrict__ ed,
    const int* __restrict__ ptr, const int* __restrict__ csr,
    const float* __restrict__ bias, float* __restrict__ out, int n) {
    int nd = blockIdx.x;
    if (nd >= n) return;
    int tid = threadIdx.x, lane = tid & 63, wid = tid >> 6;
    int beg = ptr[nd], deg = ptr[nd + 1] - beg;

    __shared__ float mden[8];     // 0..3 max, 4..7 den
    __shared__ float wred[2][4];
    __shared__ float edn_s[4];
    __shared__ int src_l[128];
    __shared__ float w_l[128 * 4];

    float4 edn = *(const float4*)&ed[(size_t)nd * 4];
    if (tid < 4) edn_s[tid] = ed[(size_t)nd * 4 + tid];

    // phase A: per-head max
    float m0 = -3.0e38f, m1 = -3.0e38f, m2 = -3.0e38f, m3 = -3.0e38f;
    for (int i = tid; i < deg; i += 128) {
        int s = csr[beg + i];
        float4 e = *(const float4*)&es[(size_t)s * 4];
        m0 = fmaxf(m0, lrelu(e.x + edn.x));
        m1 = fmaxf(m1, lrelu(e.y + edn.y));
        m2 = fmaxf(m2, lrelu(e.z + edn.z));
        m3 = fmaxf(m3, lrelu(e.w + edn.w));
    }
    #pragma unroll
    for (int off = 32; off > 0; off >>= 1) {
        m0 = fmaxf(m0, __shfl_xor(m0, off));
        m1 = fmaxf(m1, __shfl_xor(m1, off));
        m2 = fmaxf(m2, __shfl_xor(m2, off));
        m3 = fmaxf(m3, __shfl_xor(m3, off));
    }
    if (lane == 0) { wred[wid][0] = m0; wred[wid][1] = m1; wred[wid][2] = m2; wred[wid][3] = m3; }
    __syncthreads();
    if (tid == 0) {
        mden[0] = fmaxf(wred[0][0], wred[1][0]);
        mden[1] = fmaxf(wred[0][1], wred[1][1]);
        mden[2] = fmaxf(wred[0][2], wred[1][2]);
        mden[3] = fmaxf(wred[0][3], wred[1][3]);
    }
    __syncthreads();
    float M0 = mden[0], M1 = mden[1], M2 = mden[2], M3 = mden[3];

    // phase B: sum of exp
    float s0 = 0.f, s1 = 0.f, s2 = 0.f, s3 = 0.f;
    for (int i = tid; i < deg; i += 128) {
        int s = csr[beg + i];
        float4 e = *(const float4*)&es[(size_t)s * 4];
        s0 += __expf(lrelu(e.x + edn.x) - M0);
        s1 += __expf(lrelu(e.y + edn.y) - M1);
        s2 += __expf(lrelu(e.z + edn.z) - M2);
        s3 += __expf(lrelu(e.w + edn.w) - M3);
    }
    #pragma unroll
    for (int off = 32; off > 0; off >>= 1) {
        s0 += __shfl_xor(s0, off);
        s1 += __shfl_xor(s1, off);
        s2 += __shfl_xor(s2, off);
        s3 += __shfl_xor(s3, off);
    }
    if (lane == 0) { wred[wid][0] = s0; wred[wid][1] = s1; wred[wid][2] = s2; wred[wid][3] = s3; }
    __syncthreads();
    if (tid == 0) {
        mden[4] = wred[0][0] + wred[1][0];
        mden[5] = wred[0][1] + wred[1][1];
        mden[6] = wred[0][2] + wred[1][2];
        mden[7] = wred[0][3] + wred[1][3];
    }
    __syncthreads();

    // phase C: weighted accumulate, thread = channel
    int c = tid, hh = tid >> 5;
    float D = mden[4 + hh];
    float acc = 0.f;
    for (int base = 0; base < deg; base += 128) {
        int ce = min(128, deg - base);
        if (tid < ce) src_l[tid] = csr[beg + base + tid];
        __syncthreads();
        for (int idx = tid; idx < ce * 4; idx += 128) {
            int e = idx >> 2, h2 = idx & 3;
            int s = src_l[e];
            float a = lrelu(es[(size_t)s * 4 + h2] + edn_s[h2]);
            w_l[idx] = __expf(a - mden[h2]);
        }
        __syncthreads();
        #pragma unroll 4
        for (int e = 0; e < ce; ++e) {
            acc += w_l[e * 4 + hh] * Hf[(size_t)src_l[e] * 128 + c];
        }
        __syncthreads();
    }
    out[(size_t)nd * 128 + c] = acc / (D + 1e-16f) + bias[c];
}

// ---------------- batch norm ----------------
__global__ __launch_bounds__(128) void k_bn_stats(const float* __restrict__ G, float* __restrict__ sum,
                                                  float* __restrict__ sumsq, int n) {
    int c = threadIdx.x;
    float s = 0.f, s2 = 0.f;
    for (int r = blockIdx.x; r < n; r += gridDim.x) {
        float v = G[(size_t)r * 128 + c];
        s += v;
        s2 += v * v;
    }
    atomicAdd(&sum[c], s);
    atomicAdd(&sumsq[c], s2);
}

__global__ void k_bn_finalize(const float* __restrict__ sum, const float* __restrict__ sumsq,
                              const float* __restrict__ g, const float* __restrict__ be,
                              float* __restrict__ scale, float* __restrict__ shift, int n) {
    int c = threadIdx.x;  // 128
    float mean = sum[c] / (float)n;
    float var = sumsq[c] / (float)n - mean * mean;
    float sc = g[c] * rsqrtf(var + 1e-5f);
    scale[c] = sc;
    shift[c] = be[c] - mean * sc;
}

__global__ void k_bn_apply(float* __restrict__ G, const float* __restrict__ scale,
                           const float* __restrict__ shift, int total4) {
    int i = blockIdx.x * 256 + threadIdx.x;
    if (i >= total4) return;
    float4 v = ((float4*)G)[i];
    int c4 = (i & 31) * 4;
    v.x = fmaxf(v.x * scale[c4 + 0] + shift[c4 + 0], 0.f);
    v.y = fmaxf(v.y * scale[c4 + 1] + shift[c4 + 1], 0.f);
    v.z = fmaxf(v.z * scale[c4 + 2] + shift[c4 + 2], 0.f);
    v.w = fmaxf(v.w * scale[c4 + 3] + shift[c4 + 3], 0.f);
    ((float4*)G)[i] = v;
}

// ---------------- layer 3 ----------------
__global__ __launch_bounds__(256) void k_dot3(const float* __restrict__ F, const float* __restrict__ W3,
                                              float* __restrict__ h3, int n) {
    int wid = threadIdx.x >> 6, lane = threadIdx.x & 63;
    int nd = blockIdx.x * 4 + wid;
    if (nd >= n) return;
    const float* row = F + (size_t)nd * 128;
    float v = row[lane] * W3[lane] + row[lane + 64] * W3[lane + 64];
    #pragma unroll
    for (int off = 32; off > 0; off >>= 1) v += __shfl_xor(v, off);
    if (lane == 0) h3[nd] = v;
}

__global__ __launch_bounds__(64) void k_gat3(const float* __restrict__ h3, const float* __restrict__ a3s,
                                             const float* __restrict__ a3d, const float* __restrict__ b3,
                                             const int* __restrict__ ptr, const int* __restrict__ csr,
                                             float* __restrict__ out, int n) {
    int nd = blockIdx.x;
    if (nd >= n) return;
    int lane = threadIdx.x;
    int beg = ptr[nd], deg = ptr[nd + 1] - beg;
    float As = a3s[0], Ad = a3d[0], B = b3[0];
    float hd = h3[nd] * Ad;
    float m = -3.0e38f;
    for (int i = lane; i < deg; i += 64) {
        float a = lrelu(h3[csr[beg + i]] * As + hd);
        m = fmaxf(m, a);
    }
    #pragma unroll
    for (int off = 32; off > 0; off >>= 1) m = fmaxf(m, __shfl_xor(m, off));
    float den = 0.f, num = 0.f;
    for (int i = lane; i < deg; i += 64) {
        float hs = h3[csr[beg + i]];
        float a = lrelu(hs * As + hd);
        float ex = __expf(a - m);
        den += ex;
        num += ex * hs;
    }
    #pragma unroll
    for (int off = 32; off > 0; off >>= 1) {
        den += __shfl_xor(den, off);
        num += __shfl_xor(num, off);
    }
    if (lane == 0) out[nd] = fmaxf(num / (den + 1e-16f) + B, 0.f);
}

// ---------------- launch ----------------
extern "C" void kernel_launch(void* const* d_in, const int* in_sizes, int n_in,
                              void* d_out, int out_size, void* d_ws, size_t ws_size,
                              hipStream_t stream) {
    const int N_ = in_sizes[0] / 128;
    const int E_ = in_sizes[1] / 2;
    const int E2 = E_ + N_;

    const float* x = (const float*)d_in[0];
    const int* ei = (const int*)d_in[1];
    const float* W1 = (const float*)d_in[2];
    const float* a1s = (const float*)d_in[3];
    const float* a1d = (const float*)d_in[4];
    const float* b1 = (const float*)d_in[5];
    const float* g1 = (const float*)d_in[6];
    const float* be1 = (const float*)d_in[7];
    const float* W2 = (const float*)d_in[8];
    const float* a2s = (const float*)d_in[9];
    const float* a2d = (const float*)d_in[10];
    const float* b2 = (const float*)d_in[11];
    const float* g2 = (const float*)d_in[12];
    const float* be2 = (const float*)d_in[13];
    const float* W3 = (const float*)d_in[14];
    const float* a3s = (const float*)d_in[15];
    const float* a3d = (const float*)d_in[16];
    const float* b3 = (const float*)d_in[17];
    float* out = (float*)d_out;

    char* p = (char*)d_ws;
    auto alloc = [&](size_t bytes) {
        void* r = (void*)p;
        p += (bytes + 255) & ~(size_t)255;
        return r;
    };
    int* cnt = (int*)alloc((size_t)N_ * 4);
    int* rowptr = (int*)alloc((size_t)(N_ + 1) * 4);
    int* fill = (int*)alloc((size_t)N_ * 4);
    int* bsum = (int*)alloc(64 * 4);
    int* csr = (int*)alloc((size_t)E2 * 4);
    float* Hb = (float*)alloc((size_t)N_ * 128 * 4);
    float* G = (float*)alloc((size_t)N_ * 128 * 4);
    float* es = (float*)alloc((size_t)N_ * 4 * 4);
    float* ed = (float*)alloc((size_t)N_ * 4 * 4);
    float* h3 = (float*)alloc((size_t)N_ * 4);
    float* bn = (float*)alloc(512 * 4);

    int scanB = (N_ + 1023) / 1024;

    // CSR build (dst-grouped incoming edges, includes self loops)
    hipMemsetAsync(cnt, 0, (size_t)N_ * 4, stream);
    k_count<<<(E2 + 255) / 256, 256, 0, stream>>>(ei, cnt, E_, N_);
    k_scan1<<<scanB, 1024, 0, stream>>>(cnt, rowptr, bsum, N_);
    k_scan2<<<1, 64, 0, stream>>>(bsum, scanB);
    k_scan3<<<(N_ + 255) / 256, 256, 0, stream>>>(cnt, rowptr, bsum, fill, N_);
    k_scatter<<<(E2 + 255) / 256, 256, 0, stream>>>(ei, fill, csr, E_, N_);

    int gemmB = (N_ + 31) / 32;
    int scoresB = (N_ * 4 + 255) / 256;
    int applyB = (N_ * 32 + 255) / 256;

    // ----- layer 1 -----
    k_gemm128<<<gemmB, 256, 0, stream>>>(x, W1, Hb, N_);
    k_scores<<<scoresB, 256, 0, stream>>>(Hb, a1s, a1d, es, ed, N_);
    k_node_gat<<<N_, 128, 0, stream>>>(Hb, es, ed, rowptr, csr, b1, G, N_);
    hipMemsetAsync(bn, 0, 256 * 4, stream);
    k_bn_stats<<<512, 128, 0, stream>>>(G, bn, bn + 128, N_);
    k_bn_finalize<<<1, 128, 0, stream>>>(bn, bn + 128, g1, be1, bn + 256, bn + 384, N_);
    k_bn_apply<<<applyB, 256, 0, stream>>>(G, bn + 256, bn + 384, N_ * 32);

    // ----- layer 2 -----
    k_gemm128<<<gemmB, 256, 0, stream>>>(G, W2, Hb, N_);
    k_scores<<<scoresB, 256, 0, stream>>>(Hb, a2s, a2d, es, ed, N_);
    k_node_gat<<<N_, 128, 0, stream>>>(Hb, es, ed, rowptr, csr, b2, G, N_);
    hipMemsetAsync(bn, 0, 256 * 4, stream);
    k_bn_stats<<<512, 128, 0, stream>>>(G, bn, bn + 128, N_);
    k_bn_finalize<<<1, 128, 0, stream>>>(bn, bn + 128, g2, be2, bn + 256, bn + 384, N_);
    k_bn_apply<<<applyB, 256, 0, stream>>>(G, bn + 256, bn + 384, N_ * 32);

    // ----- layer 3 -----
    k_dot3<<<(N_ + 3) / 4, 256, 0, stream>>>(G, W3, h3, N_);
    k_gat3<<<N_, 64, 0, stream>>>(h3, a3s, a3d, b3, rowptr, csr, out, N_);
}

// Round 2
// 538.255 us; speedup vs baseline: 1.2749x; 1.2749x over previous
//
#include <hip/hip_runtime.h>
#include <math.h>

#define NEG_SLOPE 0.2f
#define NBMAX 256
#define CHUNK 8192
#define DCAP 16384

__device__ __forceinline__ float lrelu(float x) { return x > 0.f ? x : NEG_SLOPE * x; }

// ---------------- CSR build: 2-level bucket counting sort ----------------
// bucket b = dst >> 8 covers dst nodes [b*256, b*256+256)

__global__ __launch_bounds__(256) void k_hist(const int* __restrict__ ei, int* __restrict__ bCnt,
                                              int E, int n) {
    __shared__ int lh[NBMAX];
    int NB = (n + 255) >> 8;
    for (int i = threadIdx.x; i < NB; i += 256) lh[i] = 0;
    __syncthreads();
    int E2 = E + n;
    for (int e = blockIdx.x * 256 + threadIdx.x; e < E2; e += gridDim.x * 256) {
        int d = (e < E) ? ei[E + e] : (e - E);
        atomicAdd(&lh[d >> 8], 1);
    }
    __syncthreads();
    for (int i = threadIdx.x; i < NB; i += 256)
        if (lh[i]) atomicAdd(&bCnt[i], lh[i]);
}

__global__ __launch_bounds__(256) void k_bscan(const int* __restrict__ bCnt, int* __restrict__ bOff,
                                               int* __restrict__ bFill, int* __restrict__ rowptr,
                                               int n, int E2) {
    int NB = (n + 255) >> 8;
    int tid = threadIdx.x, lane = tid & 63, wid = tid >> 6;
    int v = (tid < NB) ? bCnt[tid] : 0;
    int s = v;
    #pragma unroll
    for (int off = 1; off < 64; off <<= 1) {
        int t = __shfl_up(s, off);
        if (lane >= off) s += t;
    }
    __shared__ int ws[4];
    if (lane == 63) ws[wid] = s;
    __syncthreads();
    if (tid == 0) {
        int c = 0;
        #pragma unroll
        for (int i = 0; i < 4; ++i) { int t = ws[i]; ws[i] = c; c += t; }
    }
    __syncthreads();
    s += ws[wid];
    int excl = s - v;
    if (tid < NB) { bOff[tid] = excl; bFill[tid] = excl; }
    if (tid == NB - 1) bOff[NB] = excl + v;
    if (tid == 0) rowptr[n] = E2;
}

__global__ __launch_bounds__(256) void k_partition(const int* __restrict__ ei, int* __restrict__ bFill,
                                                   unsigned int* __restrict__ staging, int E, int n) {
    __shared__ int lh[NBMAX];
    __shared__ int lbase[NBMAX];
    int NB = (n + 255) >> 8;
    int E2 = E + n;
    int beg = blockIdx.x * CHUNK;
    int end = min(beg + CHUNK, E2);
    for (int i = threadIdx.x; i < NB; i += 256) lh[i] = 0;
    __syncthreads();
    for (int e = beg + threadIdx.x; e < end; e += 256) {
        int d = (e < E) ? ei[E + e] : (e - E);
        atomicAdd(&lh[d >> 8], 1);
    }
    __syncthreads();
    for (int i = threadIdx.x; i < NB; i += 256) {
        int c = lh[i];
        lbase[i] = c ? atomicAdd(&bFill[i], c) : 0;
        lh[i] = 0;
    }
    __syncthreads();
    for (int e = beg + threadIdx.x; e < end; e += 256) {
        int s, d;
        if (e < E) { s = ei[e]; d = ei[E + e]; } else { s = d = e - E; }
        int b = d >> 8;
        int r = atomicAdd(&lh[b], 1);
        staging[lbase[b] + r] = ((unsigned)s << 8) | (unsigned)(d & 255);
    }
}

__global__ __launch_bounds__(256) void k_emit(const unsigned int* __restrict__ staging,
                                              const int* __restrict__ bOff, int* __restrict__ rowptr,
                                              int* __restrict__ csr, int n) {
    __shared__ int lcnt[NBMAX];
    __shared__ int lscan[NBMAX];
    __shared__ int ws[4];
    __shared__ int sorted[DCAP];  // 64 KB
    int b = blockIdx.x;
    int gbase = b << 8;
    int beg = bOff[b], end = bOff[b + 1], m = end - beg;
    int tid = threadIdx.x, lane = tid & 63, wid = tid >> 6;

    lcnt[tid] = 0;
    __syncthreads();
    for (int j = tid; j < m; j += 256) atomicAdd(&lcnt[staging[beg + j] & 255], 1);
    __syncthreads();
    // exclusive scan of 256 counters
    int v = lcnt[tid];
    int s = v;
    #pragma unroll
    for (int off = 1; off < 64; off <<= 1) {
        int t = __shfl_up(s, off);
        if (lane >= off) s += t;
    }
    if (lane == 63) ws[wid] = s;
    __syncthreads();
    if (tid == 0) {
        int c = 0;
        #pragma unroll
        for (int i = 0; i < 4; ++i) { int t = ws[i]; ws[i] = c; c += t; }
    }
    __syncthreads();
    int excl = s + ws[wid] - v;
    lscan[tid] = excl;
    lcnt[tid] = 0;  // reuse as fill counter
    __syncthreads();

    if (gbase + tid < n) rowptr[gbase + tid] = beg + lscan[tid];

    if (m <= DCAP) {
        for (int j = tid; j < m; j += 256) {
            unsigned e = staging[beg + j];
            int ld = e & 255;
            int src = e >> 8;
            int r = atomicAdd(&lcnt[ld], 1);
            sorted[lscan[ld] + r] = src;
        }
        __syncthreads();
        for (int j = tid; j < m; j += 256) csr[beg + j] = sorted[j];
    } else {
        for (int j = tid; j < m; j += 256) {
            unsigned e = staging[beg + j];
            int ld = e & 255;
            int src = e >> 8;
            int r = atomicAdd(&lcnt[ld], 1);
            csr[beg + lscan[ld] + r] = src;
        }
    }
}

// ---------------- GEMM: H = X @ W, K=128, Ncols=128 ----------------
__global__ __launch_bounds__(256) void k_gemm128(const float* __restrict__ X, const float* __restrict__ W,
                                                 float* __restrict__ Hout, int n) {
    __shared__ float Wl[64 * 128];  // 32 KB: K-half of W
    __shared__ float Xl[64 * 32];   // 8 KB: 32 rows x 64 k, swizzled
    int tid = threadIdx.x;
    int row0 = blockIdx.x * 32;
    int cg = tid & 31, ng = tid >> 5;
    int c0 = cg * 4, r0 = ng * 4;
    float acc[4][4] = {{0.f}};
    for (int kb = 0; kb < 128; kb += 64) {
        const float4* Wg = (const float4*)(W + (size_t)kb * 128);
        float4* Wl4 = (float4*)Wl;
        #pragma unroll
        for (int j = 0; j < 8; ++j) Wl4[tid + j * 256] = Wg[tid + j * 256];
        #pragma unroll
        for (int j = 0; j < 2; ++j) {
            int idx = tid + j * 256;  // 512 float4
            int r = idx >> 4;         // 0..31
            int k4 = idx & 15;        // 0..15
            float4 v = make_float4(0.f, 0.f, 0.f, 0.f);
            if (row0 + r < n) v = ((const float4*)(X + (size_t)(row0 + r) * 128 + kb))[k4];
            int k = k4 * 4;
            Xl[(k + 0) * 32 + (r ^ ((k + 0) & 31))] = v.x;
            Xl[(k + 1) * 32 + (r ^ ((k + 1) & 31))] = v.y;
            Xl[(k + 2) * 32 + (r ^ ((k + 2) & 31))] = v.z;
            Xl[(k + 3) * 32 + (r ^ ((k + 3) & 31))] = v.w;
        }
        __syncthreads();
        #pragma unroll
        for (int k = 0; k < 64; ++k) {
            float4 wv = *(const float4*)&Wl[k * 128 + c0];
            float x0 = Xl[k * 32 + ((r0 + 0) ^ (k & 31))];
            float x1 = Xl[k * 32 + ((r0 + 1) ^ (k & 31))];
            float x2 = Xl[k * 32 + ((r0 + 2) ^ (k & 31))];
            float x3 = Xl[k * 32 + ((r0 + 3) ^ (k & 31))];
            acc[0][0] += x0 * wv.x; acc[0][1] += x0 * wv.y; acc[0][2] += x0 * wv.z; acc[0][3] += x0 * wv.w;
            acc[1][0] += x1 * wv.x; acc[1][1] += x1 * wv.y; acc[1][2] += x1 * wv.z; acc[1][3] += x1 * wv.w;
            acc[2][0] += x2 * wv.x; acc[2][1] += x2 * wv.y; acc[2][2] += x2 * wv.z; acc[2][3] += x2 * wv.w;
            acc[3][0] += x3 * wv.x; acc[3][1] += x3 * wv.y; acc[3][2] += x3 * wv.z; acc[3][3] += x3 * wv.w;
        }
        __syncthreads();
    }
    #pragma unroll
    for (int i = 0; i < 4; ++i) {
        int r = row0 + r0 + i;
        if (r < n)
            *(float4*)&Hout[(size_t)r * 128 + c0] =
                make_float4(acc[i][0], acc[i][1], acc[i][2], acc[i][3]);
    }
}

// ---------------- attention scores: es/ed [N,4] ----------------
__global__ void k_scores(const float* __restrict__ H, const float* __restrict__ as_,
                         const float* __restrict__ ad_, float* __restrict__ es,
                         float* __restrict__ ed, int n) {
    int i = blockIdx.x * 256 + threadIdx.x;  // over n*4
    if (i >= n * 4) return;
    int nd = i >> 2, h = i & 3;
    const float4* hp = (const float4*)(H + (size_t)nd * 128 + h * 32);
    const float4* sp = (const float4*)(as_ + h * 32);
    const float4* dp = (const float4*)(ad_ + h * 32);
    float s = 0.f, d = 0.f;
    #pragma unroll
    for (int j = 0; j < 8; ++j) {
        float4 hv = hp[j], sv = sp[j], dv = dp[j];
        s += hv.x * sv.x + hv.y * sv.y + hv.z * sv.z + hv.w * sv.w;
        d += hv.x * dv.x + hv.y * dv.y + hv.z * dv.z + hv.w * dv.w;
    }
    es[i] = s;
    ed[i] = d;
}

// ---------------- per-node GAT softmax + aggregate (H=4, C=32) ----------------
__global__ __launch_bounds__(128) void k_node_gat(
    const float* __restrict__ Hf, const float* __restrict__ es, const float* __restrict__ ed,
    const int* __restrict__ ptr, const int* __restrict__ csr,
    const float* __restrict__ bias, float* __restrict__ out, int n) {
    int nd = blockIdx.x;
    if (nd >= n) return;
    int tid = threadIdx.x, lane = tid & 63, wid = tid >> 6;
    int beg = ptr[nd], deg = ptr[nd + 1] - beg;

    __shared__ float mden[8];     // 0..3 max, 4..7 den
    __shared__ float wred[2][4];
    __shared__ float edn_s[4];
    __shared__ int src_l[128];
    __shared__ float w_l[128 * 4];

    float4 edn = *(const float4*)&ed[(size_t)nd * 4];
    if (tid < 4) edn_s[tid] = ed[(size_t)nd * 4 + tid];

    // phase A: per-head max
    float m0 = -3.0e38f, m1 = -3.0e38f, m2 = -3.0e38f, m3 = -3.0e38f;
    for (int i = tid; i < deg; i += 128) {
        int s = csr[beg + i];
        float4 e = *(const float4*)&es[(size_t)s * 4];
        m0 = fmaxf(m0, lrelu(e.x + edn.x));
        m1 = fmaxf(m1, lrelu(e.y + edn.y));
        m2 = fmaxf(m2, lrelu(e.z + edn.z));
        m3 = fmaxf(m3, lrelu(e.w + edn.w));
    }
    #pragma unroll
    for (int off = 32; off > 0; off >>= 1) {
        m0 = fmaxf(m0, __shfl_xor(m0, off));
        m1 = fmaxf(m1, __shfl_xor(m1, off));
        m2 = fmaxf(m2, __shfl_xor(m2, off));
        m3 = fmaxf(m3, __shfl_xor(m3, off));
    }
    if (lane == 0) { wred[wid][0] = m0; wred[wid][1] = m1; wred[wid][2] = m2; wred[wid][3] = m3; }
    __syncthreads();
    if (tid == 0) {
        mden[0] = fmaxf(wred[0][0], wred[1][0]);
        mden[1] = fmaxf(wred[0][1], wred[1][1]);
        mden[2] = fmaxf(wred[0][2], wred[1][2]);
        mden[3] = fmaxf(wred[0][3], wred[1][3]);
    }
    __syncthreads();
    float M0 = mden[0], M1 = mden[1], M2 = mden[2], M3 = mden[3];

    // phase B: sum of exp
    float s0 = 0.f, s1 = 0.f, s2 = 0.f, s3 = 0.f;
    for (int i = tid; i < deg; i += 128) {
        int s = csr[beg + i];
        float4 e = *(const float4*)&es[(size_t)s * 4];
        s0 += __expf(lrelu(e.x + edn.x) - M0);
        s1 += __expf(lrelu(e.y + edn.y) - M1);
        s2 += __expf(lrelu(e.z + edn.z) - M2);
        s3 += __expf(lrelu(e.w + edn.w) - M3);
    }
    #pragma unroll
    for (int off = 32; off > 0; off >>= 1) {
        s0 += __shfl_xor(s0, off);
        s1 += __shfl_xor(s1, off);
        s2 += __shfl_xor(s2, off);
        s3 += __shfl_xor(s3, off);
    }
    if (lane == 0) { wred[wid][0] = s0; wred[wid][1] = s1; wred[wid][2] = s2; wred[wid][3] = s3; }
    __syncthreads();
    if (tid == 0) {
        mden[4] = wred[0][0] + wred[1][0];
        mden[5] = wred[0][1] + wred[1][1];
        mden[6] = wred[0][2] + wred[1][2];
        mden[7] = wred[0][3] + wred[1][3];
    }
    __syncthreads();

    // phase C: weighted accumulate, thread = channel
    int c = tid, hh = tid >> 5;
    float D = mden[4 + hh];
    float acc = 0.f;
    for (int base = 0; base < deg; base += 128) {
        int ce = min(128, deg - base);
        if (tid < ce) src_l[tid] = csr[beg + base + tid];
        __syncthreads();
        for (int idx = tid; idx < ce * 4; idx += 128) {
            int e = idx >> 2, h2 = idx & 3;
            int s = src_l[e];
            float a = lrelu(es[(size_t)s * 4 + h2] + edn_s[h2]);
            w_l[idx] = __expf(a - mden[h2]);
        }
        __syncthreads();
        #pragma unroll 4
        for (int e = 0; e < ce; ++e) {
            acc += w_l[e * 4 + hh] * Hf[(size_t)src_l[e] * 128 + c];
        }
        __syncthreads();
    }
    out[(size_t)nd * 128 + c] = acc / (D + 1e-16f) + bias[c];
}

// ---------------- batch norm ----------------
__global__ __launch_bounds__(128) void k_bn_stats(const float* __restrict__ G, float* __restrict__ sum,
                                                  float* __restrict__ sumsq, int n) {
    int c = threadIdx.x;
    float s = 0.f, s2 = 0.f;
    for (int r = blockIdx.x; r < n; r += gridDim.x) {
        float v = G[(size_t)r * 128 + c];
        s += v;
        s2 += v * v;
    }
    atomicAdd(&sum[c], s);
    atomicAdd(&sumsq[c], s2);
}

__global__ void k_bn_finalize(const float* __restrict__ sum, const float* __restrict__ sumsq,
                              const float* __restrict__ g, const float* __restrict__ be,
                              float* __restrict__ scale, float* __restrict__ shift, int n) {
    int c = threadIdx.x;  // 128
    float mean = sum[c] / (float)n;
    float var = sumsq[c] / (float)n - mean * mean;
    float sc = g[c] * rsqrtf(var + 1e-5f);
    scale[c] = sc;
    shift[c] = be[c] - mean * sc;
}

__global__ void k_bn_apply(float* __restrict__ G, const float* __restrict__ scale,
                           const float* __restrict__ shift, int total4) {
    int i = blockIdx.x * 256 + threadIdx.x;
    if (i >= total4) return;
    float4 v = ((float4*)G)[i];
    int c4 = (i & 31) * 4;
    v.x = fmaxf(v.x * scale[c4 + 0] + shift[c4 + 0], 0.f);
    v.y = fmaxf(v.y * scale[c4 + 1] + shift[c4 + 1], 0.f);
    v.z = fmaxf(v.z * scale[c4 + 2] + shift[c4 + 2], 0.f);
    v.w = fmaxf(v.w * scale[c4 + 3] + shift[c4 + 3], 0.f);
    ((float4*)G)[i] = v;
}

// ---------------- layer 3 ----------------
__global__ __launch_bounds__(256) void k_dot3(const float* __restrict__ F, const float* __restrict__ W3,
                                              float* __restrict__ h3, int n) {
    int wid = threadIdx.x >> 6, lane = threadIdx.x & 63;
    int nd = blockIdx.x * 4 + wid;
    if (nd >= n) return;
    const float* row = F + (size_t)nd * 128;
    float v = row[lane] * W3[lane] + row[lane + 64] * W3[lane + 64];
    #pragma unroll
    for (int off = 32; off > 0; off >>= 1) v += __shfl_xor(v, off);
    if (lane == 0) h3[nd] = v;
}

__global__ __launch_bounds__(64) void k_gat3(const float* __restrict__ h3, const float* __restrict__ a3s,
                                             const float* __restrict__ a3d, const float* __restrict__ b3,
                                             const int* __restrict__ ptr, const int* __restrict__ csr,
                                             float* __restrict__ out, int n) {
    int nd = blockIdx.x;
    if (nd >= n) return;
    int lane = threadIdx.x;
    int beg = ptr[nd], deg = ptr[nd + 1] - beg;
    float As = a3s[0], Ad = a3d[0], B = b3[0];
    float hd = h3[nd] * Ad;
    float m = -3.0e38f;
    for (int i = lane; i < deg; i += 64) {
        float a = lrelu(h3[csr[beg + i]] * As + hd);
        m = fmaxf(m, a);
    }
    #pragma unroll
    for (int off = 32; off > 0; off >>= 1) m = fmaxf(m, __shfl_xor(m, off));
    float den = 0.f, num = 0.f;
    for (int i = lane; i < deg; i += 64) {
        float hs = h3[csr[beg + i]];
        float a = lrelu(hs * As + hd);
        float ex = __expf(a - m);
        den += ex;
        num += ex * hs;
    }
    #pragma unroll
    for (int off = 32; off > 0; off >>= 1) {
        den += __shfl_xor(den, off);
        num += __shfl_xor(num, off);
    }
    if (lane == 0) out[nd] = fmaxf(num / (den + 1e-16f) + B, 0.f);
}

// ---------------- launch ----------------
extern "C" void kernel_launch(void* const* d_in, const int* in_sizes, int n_in,
                              void* d_out, int out_size, void* d_ws, size_t ws_size,
                              hipStream_t stream) {
    const int N_ = in_sizes[0] / 128;
    const int E_ = in_sizes[1] / 2;
    const int E2 = E_ + N_;
    const int NB = (N_ + 255) >> 8;

    const float* x = (const float*)d_in[0];
    const int* ei = (const int*)d_in[1];
    const float* W1 = (const float*)d_in[2];
    const float* a1s = (const float*)d_in[3];
    const float* a1d = (const float*)d_in[4];
    const float* b1 = (const float*)d_in[5];
    const float* g1 = (const float*)d_in[6];
    const float* be1 = (const float*)d_in[7];
    const float* W2 = (const float*)d_in[8];
    const float* a2s = (const float*)d_in[9];
    const float* a2d = (const float*)d_in[10];
    const float* b2 = (const float*)d_in[11];
    const float* g2 = (const float*)d_in[12];
    const float* be2 = (const float*)d_in[13];
    const float* W3 = (const float*)d_in[14];
    const float* a3s = (const float*)d_in[15];
    const float* a3d = (const float*)d_in[16];
    const float* b3 = (const float*)d_in[17];
    float* out = (float*)d_out;

    char* p = (char*)d_ws;
    auto alloc = [&](size_t bytes) {
        void* r = (void*)p;
        p += (bytes + 255) & ~(size_t)255;
        return r;
    };
    int* bCnt = (int*)alloc((size_t)NBMAX * 4);
    int* bOff = (int*)alloc((size_t)(NBMAX + 1) * 4);
    int* bFill = (int*)alloc((size_t)NBMAX * 4);
    int* rowptr = (int*)alloc((size_t)(N_ + 1) * 4);
    unsigned int* staging = (unsigned int*)alloc((size_t)E2 * 4);
    int* csr = (int*)alloc((size_t)E2 * 4);
    float* Hb = (float*)alloc((size_t)N_ * 128 * 4);
    float* G = (float*)alloc((size_t)N_ * 128 * 4);
    float* es = (float*)alloc((size_t)N_ * 4 * 4);
    float* ed = (float*)alloc((size_t)N_ * 4 * 4);
    float* h3 = (float*)alloc((size_t)N_ * 4);
    float* bn = (float*)alloc(512 * 4);

    // CSR build (dst-grouped incoming edges incl self loops), bucket counting sort
    hipMemsetAsync(bCnt, 0, (size_t)NBMAX * 4, stream);
    k_hist<<<512, 256, 0, stream>>>(ei, bCnt, E_, N_);
    k_bscan<<<1, 256, 0, stream>>>(bCnt, bOff, bFill, rowptr, N_, E2);
    k_partition<<<(E2 + CHUNK - 1) / CHUNK, 256, 0, stream>>>(ei, bFill, staging, E_, N_);
    k_emit<<<NB, 256, 0, stream>>>(staging, bOff, rowptr, csr, N_);

    int gemmB = (N_ + 31) / 32;
    int scoresB = (N_ * 4 + 255) / 256;
    int applyB = (N_ * 32 + 255) / 256;

    // ----- layer 1 -----
    k_gemm128<<<gemmB, 256, 0, stream>>>(x, W1, Hb, N_);
    k_scores<<<scoresB, 256, 0, stream>>>(Hb, a1s, a1d, es, ed, N_);
    k_node_gat<<<N_, 128, 0, stream>>>(Hb, es, ed, rowptr, csr, b1, G, N_);
    hipMemsetAsync(bn, 0, 256 * 4, stream);
    k_bn_stats<<<512, 128, 0, stream>>>(G, bn, bn + 128, N_);
    k_bn_finalize<<<1, 128, 0, stream>>>(bn, bn + 128, g1, be1, bn + 256, bn + 384, N_);
    k_bn_apply<<<applyB, 256, 0, stream>>>(G, bn + 256, bn + 384, N_ * 32);

    // ----- layer 2 -----
    k_gemm128<<<gemmB, 256, 0, stream>>>(G, W2, Hb, N_);
    k_scores<<<scoresB, 256, 0, stream>>>(Hb, a2s, a2d, es, ed, N_);
    k_node_gat<<<N_, 128, 0, stream>>>(Hb, es, ed, rowptr, csr, b2, G, N_);
    hipMemsetAsync(bn, 0, 256 * 4, stream);
    k_bn_stats<<<512, 128, 0, stream>>>(G, bn, bn + 128, N_);
    k_bn_finalize<<<1, 128, 0, stream>>>(bn, bn + 128, g2, be2, bn + 256, bn + 384, N_);
    k_bn_apply<<<applyB, 256, 0, stream>>>(G, bn + 256, bn + 384, N_ * 32);

    // ----- layer 3 -----
    k_dot3<<<(N_ + 3) / 4, 256, 0, stream>>>(G, W3, h3, N_);
    k_gat3<<<N_, 64, 0, stream>>>(h3, a3s, a3d, b3, rowptr, csr, out, N_);
}

// Round 3
// 486.454 us; speedup vs baseline: 1.4106x; 1.1065x over previous
//
#include <hip/hip_runtime.h>
#include <math.h>

#define NEG_SLOPE 0.2f
#define NBMAX 256
#define CHUNK 8192
#define DCAP 16384

__device__ __forceinline__ float lrelu(float x) { return x > 0.f ? x : NEG_SLOPE * x; }

// ---------------- CSR build: 2-level bucket counting sort ----------------
__global__ __launch_bounds__(256) void k_hist(const int* __restrict__ ei, int* __restrict__ bCnt,
                                              int E, int n) {
    __shared__ int lh[NBMAX];
    int NB = (n + 255) >> 8;
    for (int i = threadIdx.x; i < NB; i += 256) lh[i] = 0;
    __syncthreads();
    int E2 = E + n;
    for (int e = blockIdx.x * 256 + threadIdx.x; e < E2; e += gridDim.x * 256) {
        int d = (e < E) ? ei[E + e] : (e - E);
        atomicAdd(&lh[d >> 8], 1);
    }
    __syncthreads();
    for (int i = threadIdx.x; i < NB; i += 256)
        if (lh[i]) atomicAdd(&bCnt[i], lh[i]);
}

__global__ __launch_bounds__(256) void k_bscan(const int* __restrict__ bCnt, int* __restrict__ bOff,
                                               int* __restrict__ bFill, int* __restrict__ rowptr,
                                               int n, int E2) {
    int NB = (n + 255) >> 8;
    int tid = threadIdx.x, lane = tid & 63, wid = tid >> 6;
    int v = (tid < NB) ? bCnt[tid] : 0;
    int s = v;
    #pragma unroll
    for (int off = 1; off < 64; off <<= 1) {
        int t = __shfl_up(s, off);
        if (lane >= off) s += t;
    }
    __shared__ int ws[4];
    if (lane == 63) ws[wid] = s;
    __syncthreads();
    if (tid == 0) {
        int c = 0;
        #pragma unroll
        for (int i = 0; i < 4; ++i) { int t = ws[i]; ws[i] = c; c += t; }
    }
    __syncthreads();
    s += ws[wid];
    int excl = s - v;
    if (tid < NB) { bOff[tid] = excl; bFill[tid] = excl; }
    if (tid == NB - 1) bOff[NB] = excl + v;
    if (tid == 0) rowptr[n] = E2;
}

__global__ __launch_bounds__(256) void k_partition(const int* __restrict__ ei, int* __restrict__ bFill,
                                                   unsigned int* __restrict__ staging, int E, int n) {
    __shared__ int lh[NBMAX];
    __shared__ int lbase[NBMAX];
    int NB = (n + 255) >> 8;
    int E2 = E + n;
    int beg = blockIdx.x * CHUNK;
    int end = min(beg + CHUNK, E2);
    for (int i = threadIdx.x; i < NB; i += 256) lh[i] = 0;
    __syncthreads();
    for (int e = beg + threadIdx.x; e < end; e += 256) {
        int d = (e < E) ? ei[E + e] : (e - E);
        atomicAdd(&lh[d >> 8], 1);
    }
    __syncthreads();
    for (int i = threadIdx.x; i < NB; i += 256) {
        int c = lh[i];
        lbase[i] = c ? atomicAdd(&bFill[i], c) : 0;
        lh[i] = 0;
    }
    __syncthreads();
    for (int e = beg + threadIdx.x; e < end; e += 256) {
        int s, d;
        if (e < E) { s = ei[e]; d = ei[E + e]; } else { s = d = e - E; }
        int b = d >> 8;
        int r = atomicAdd(&lh[b], 1);
        staging[lbase[b] + r] = ((unsigned)s << 8) | (unsigned)(d & 255);
    }
}

__global__ __launch_bounds__(256) void k_emit(const unsigned int* __restrict__ staging,
                                              const int* __restrict__ bOff, int* __restrict__ rowptr,
                                              int* __restrict__ csr, int n) {
    __shared__ int lcnt[NBMAX];
    __shared__ int lscan[NBMAX];
    __shared__ int ws[4];
    __shared__ int sorted[DCAP];  // 64 KB
    int b = blockIdx.x;
    int gbase = b << 8;
    int beg = bOff[b], end = bOff[b + 1], m = end - beg;
    int tid = threadIdx.x, lane = tid & 63, wid = tid >> 6;

    lcnt[tid] = 0;
    __syncthreads();
    for (int j = tid; j < m; j += 256) atomicAdd(&lcnt[staging[beg + j] & 255], 1);
    __syncthreads();
    int v = lcnt[tid];
    int s = v;
    #pragma unroll
    for (int off = 1; off < 64; off <<= 1) {
        int t = __shfl_up(s, off);
        if (lane >= off) s += t;
    }
    if (lane == 63) ws[wid] = s;
    __syncthreads();
    if (tid == 0) {
        int c = 0;
        #pragma unroll
        for (int i = 0; i < 4; ++i) { int t = ws[i]; ws[i] = c; c += t; }
    }
    __syncthreads();
    int excl = s + ws[wid] - v;
    lscan[tid] = excl;
    lcnt[tid] = 0;
    __syncthreads();

    if (gbase + tid < n) rowptr[gbase + tid] = beg + lscan[tid];

    if (m <= DCAP) {
        for (int j = tid; j < m; j += 256) {
            unsigned e = staging[beg + j];
            int ld = e & 255;
            int src = e >> 8;
            int r = atomicAdd(&lcnt[ld], 1);
            sorted[lscan[ld] + r] = src;
        }
        __syncthreads();
        for (int j = tid; j < m; j += 256) csr[beg + j] = sorted[j];
    } else {
        for (int j = tid; j < m; j += 256) {
            unsigned e = staging[beg + j];
            int ld = e & 255;
            int src = e >> 8;
            int r = atomicAdd(&lcnt[ld], 1);
            csr[beg + lscan[ld] + r] = src;
        }
    }
}

// ---------------- GEMM: H = relu(X*scale+shift) @ W, fused es/ed epilogue ----------------
__global__ __launch_bounds__(256) void k_gemm128(const float* __restrict__ X, const float* __restrict__ W,
                                                 float* __restrict__ Hout,
                                                 const float* __restrict__ scale, const float* __restrict__ shift,
                                                 const float* __restrict__ as_f, const float* __restrict__ ad_f,
                                                 float* __restrict__ es, float* __restrict__ ed, int n) {
    __shared__ float Wl[64 * 128];  // 32 KB
    __shared__ float Xl[64 * 32];   // 8 KB, swizzled
    int tid = threadIdx.x;
    int row0 = blockIdx.x * 32;
    int cg = tid & 31, ng = tid >> 5;
    int c0 = cg * 4, r0 = ng * 4;
    float acc[4][4] = {{0.f}};
    for (int kb = 0; kb < 128; kb += 64) {
        const float4* Wg = (const float4*)(W + (size_t)kb * 128);
        float4* Wl4 = (float4*)Wl;
        #pragma unroll
        for (int j = 0; j < 8; ++j) Wl4[tid + j * 256] = Wg[tid + j * 256];
        #pragma unroll
        for (int j = 0; j < 2; ++j) {
            int idx = tid + j * 256;
            int r = idx >> 4;
            int k4 = idx & 15;
            float4 v = make_float4(0.f, 0.f, 0.f, 0.f);
            if (row0 + r < n) v = ((const float4*)(X + (size_t)(row0 + r) * 128 + kb))[k4];
            if (scale) {
                int kc = kb + k4 * 4;
                float4 sc = *(const float4*)&scale[kc];
                float4 sh = *(const float4*)&shift[kc];
                v.x = fmaxf(v.x * sc.x + sh.x, 0.f);
                v.y = fmaxf(v.y * sc.y + sh.y, 0.f);
                v.z = fmaxf(v.z * sc.z + sh.z, 0.f);
                v.w = fmaxf(v.w * sc.w + sh.w, 0.f);
            }
            int k = k4 * 4;
            Xl[(k + 0) * 32 + (r ^ ((k + 0) & 31))] = v.x;
            Xl[(k + 1) * 32 + (r ^ ((k + 1) & 31))] = v.y;
            Xl[(k + 2) * 32 + (r ^ ((k + 2) & 31))] = v.z;
            Xl[(k + 3) * 32 + (r ^ ((k + 3) & 31))] = v.w;
        }
        __syncthreads();
        #pragma unroll
        for (int k = 0; k < 64; ++k) {
            float4 wv = *(const float4*)&Wl[k * 128 + c0];
            float x0 = Xl[k * 32 + ((r0 + 0) ^ (k & 31))];
            float x1 = Xl[k * 32 + ((r0 + 1) ^ (k & 31))];
            float x2 = Xl[k * 32 + ((r0 + 2) ^ (k & 31))];
            float x3 = Xl[k * 32 + ((r0 + 3) ^ (k & 31))];
            acc[0][0] += x0 * wv.x; acc[0][1] += x0 * wv.y; acc[0][2] += x0 * wv.z; acc[0][3] += x0 * wv.w;
            acc[1][0] += x1 * wv.x; acc[1][1] += x1 * wv.y; acc[1][2] += x1 * wv.z; acc[1][3] += x1 * wv.w;
            acc[2][0] += x2 * wv.x; acc[2][1] += x2 * wv.y; acc[2][2] += x2 * wv.z; acc[2][3] += x2 * wv.w;
            acc[3][0] += x3 * wv.x; acc[3][1] += x3 * wv.y; acc[3][2] += x3 * wv.z; acc[3][3] += x3 * wv.w;
        }
        __syncthreads();
    }
    #pragma unroll
    for (int i = 0; i < 4; ++i) {
        int r = row0 + r0 + i;
        if (r < n)
            *(float4*)&Hout[(size_t)r * 128 + c0] =
                make_float4(acc[i][0], acc[i][1], acc[i][2], acc[i][3]);
    }
    // fused attention-score epilogue: es[r,h] / ed[r,h]
    float4 asv = *(const float4*)&as_f[c0];
    float4 adv = *(const float4*)&ad_f[c0];
    float ps[4], pd[4];
    #pragma unroll
    for (int i = 0; i < 4; ++i) {
        ps[i] = acc[i][0] * asv.x + acc[i][1] * asv.y + acc[i][2] * asv.z + acc[i][3] * asv.w;
        pd[i] = acc[i][0] * adv.x + acc[i][1] * adv.y + acc[i][2] * adv.z + acc[i][3] * adv.w;
    }
    #pragma unroll
    for (int off = 1; off <= 4; off <<= 1) {
        #pragma unroll
        for (int i = 0; i < 4; ++i) {
            ps[i] += __shfl_xor(ps[i], off);
            pd[i] += __shfl_xor(pd[i], off);
        }
    }
    if ((cg & 7) == 0) {
        int hh = cg >> 3;
        #pragma unroll
        for (int i = 0; i < 4; ++i) {
            int r = row0 + r0 + i;
            if (r < n) {
                es[(size_t)r * 4 + hh] = ps[i];
                ed[(size_t)r * 4 + hh] = pd[i];
            }
        }
    }
}

// ---------------- per-node GAT: single-pass softmax+aggregate (no-max, shift=16) ----------------
__global__ __launch_bounds__(128) void k_node_gat(
    const float* __restrict__ Hf, const float* __restrict__ es, const float* __restrict__ ed,
    const int* __restrict__ ptr, const int* __restrict__ csr,
    const float* __restrict__ bias, float* __restrict__ out, int n) {
    int nd = blockIdx.x;
    if (nd >= n) return;
    int tid = threadIdx.x, lane = tid & 63, wid = tid >> 6;
    int cg = tid & 31;    // float4 channel group
    int slot = tid >> 5;  // 0..3 edge slot
    int hh = cg >> 3;     // head of my channels
    int beg = ptr[nd], deg = ptr[nd + 1] - beg;

    __shared__ int src_l[128];
    __shared__ float w_l[128 * 4];
    __shared__ float wdred[2][4];
    __shared__ float dens[4];
    __shared__ float accred[4][32];

    float4 edn = *(const float4*)&ed[(size_t)nd * 4];
    float d0 = 0.f, d1 = 0.f, d2 = 0.f, d3 = 0.f;
    float4 acc = make_float4(0.f, 0.f, 0.f, 0.f);
    const float4* H4 = (const float4*)Hf;
    const float4* es4 = (const float4*)es;

    for (int base = 0; base < deg; base += 128) {
        int ce = min(128, deg - base);
        __syncthreads();
        if (tid < ce) {
            int s = csr[beg + base + tid];
            src_l[tid] = s;
            float4 ev = es4[s];
            float w0 = __expf(lrelu(ev.x + edn.x) - 16.f);
            float w1 = __expf(lrelu(ev.y + edn.y) - 16.f);
            float w2 = __expf(lrelu(ev.z + edn.z) - 16.f);
            float w3 = __expf(lrelu(ev.w + edn.w) - 16.f);
            d0 += w0; d1 += w1; d2 += w2; d3 += w3;
            *(float4*)&w_l[tid * 4] = make_float4(w0, w1, w2, w3);
        }
        __syncthreads();
        for (int e = slot; e < ce; e += 4) {
            int s = src_l[e];
            float w = w_l[e * 4 + hh];
            float4 hv = H4[(size_t)s * 32 + cg];
            acc.x += w * hv.x;
            acc.y += w * hv.y;
            acc.z += w * hv.z;
            acc.w += w * hv.w;
        }
    }
    // den reduce across 128 threads
    #pragma unroll
    for (int off = 1; off <= 32; off <<= 1) {
        d0 += __shfl_xor(d0, off);
        d1 += __shfl_xor(d1, off);
        d2 += __shfl_xor(d2, off);
        d3 += __shfl_xor(d3, off);
    }
    if (lane == 0) { wdred[wid][0] = d0; wdred[wid][1] = d1; wdred[wid][2] = d2; wdred[wid][3] = d3; }
    // slot-pair reduce within wave
    acc.x += __shfl_xor(acc.x, 32);
    acc.y += __shfl_xor(acc.y, 32);
    acc.z += __shfl_xor(acc.z, 32);
    acc.w += __shfl_xor(acc.w, 32);
    __syncthreads();
    if (tid == 0) {
        dens[0] = wdred[0][0] + wdred[1][0];
        dens[1] = wdred[0][1] + wdred[1][1];
        dens[2] = wdred[0][2] + wdred[1][2];
        dens[3] = wdred[0][3] + wdred[1][3];
    }
    if (wid == 1 && lane < 32) {
        accred[0][lane] = acc.x;
        accred[1][lane] = acc.y;
        accred[2][lane] = acc.z;
        accred[3][lane] = acc.w;
    }
    __syncthreads();
    if (tid < 32) {
        acc.x += accred[0][tid];
        acc.y += accred[1][tid];
        acc.z += accred[2][tid];
        acc.w += accred[3][tid];
        float D = dens[hh] + 1e-16f;
        float inv = 1.f / D;
        float4 bv = *(const float4*)&bias[cg * 4];
        float4 o = make_float4(acc.x * inv + bv.x, acc.y * inv + bv.y,
                               acc.z * inv + bv.z, acc.w * inv + bv.w);
        *(float4*)&out[(size_t)nd * 128 + cg * 4] = o;
    }
}

// ---------------- batch norm stats ----------------
__global__ __launch_bounds__(128) void k_bn_stats(const float* __restrict__ G, float* __restrict__ sum,
                                                  float* __restrict__ sumsq, int n) {
    int c = threadIdx.x;
    float s = 0.f, s2 = 0.f;
    for (int r = blockIdx.x; r < n; r += gridDim.x) {
        float v = G[(size_t)r * 128 + c];
        s += v;
        s2 += v * v;
    }
    atomicAdd(&sum[c], s);
    atomicAdd(&sumsq[c], s2);
}

__global__ void k_bn_finalize(const float* __restrict__ sum, const float* __restrict__ sumsq,
                              const float* __restrict__ g, const float* __restrict__ be,
                              float* __restrict__ scale, float* __restrict__ shift, int n) {
    int c = threadIdx.x;  // 128
    float mean = sum[c] / (float)n;
    float var = sumsq[c] / (float)n - mean * mean;
    float sc = g[c] * rsqrtf(var + 1e-5f);
    scale[c] = sc;
    shift[c] = be[c] - mean * sc;
}

// ---------------- layer 3 (BN+ReLU fused into dot) ----------------
__global__ __launch_bounds__(256) void k_dot3(const float* __restrict__ F, const float* __restrict__ W3,
                                              const float* __restrict__ scale, const float* __restrict__ shift,
                                              float* __restrict__ h3, int n) {
    int wid = threadIdx.x >> 6, lane = threadIdx.x & 63;
    int nd = blockIdx.x * 4 + wid;
    if (nd >= n) return;
    const float* row = F + (size_t)nd * 128;
    float v0 = fmaxf(row[lane] * scale[lane] + shift[lane], 0.f);
    float v1 = fmaxf(row[lane + 64] * scale[lane + 64] + shift[lane + 64], 0.f);
    float v = v0 * W3[lane] + v1 * W3[lane + 64];
    #pragma unroll
    for (int off = 32; off > 0; off >>= 1) v += __shfl_xor(v, off);
    if (lane == 0) h3[nd] = v;
}

__global__ __launch_bounds__(64) void k_gat3(const float* __restrict__ h3, const float* __restrict__ a3s,
                                             const float* __restrict__ a3d, const float* __restrict__ b3,
                                             const int* __restrict__ ptr, const int* __restrict__ csr,
                                             float* __restrict__ out, int n) {
    int nd = blockIdx.x;
    if (nd >= n) return;
    int lane = threadIdx.x;
    int beg = ptr[nd], deg = ptr[nd + 1] - beg;
    float As = a3s[0], Ad = a3d[0], B = b3[0];
    float hd = h3[nd] * Ad;
    float den = 0.f, num = 0.f;
    for (int i = lane; i < deg; i += 64) {
        float hs = h3[csr[beg + i]];
        float a = lrelu(hs * As + hd);
        float ex = __expf(a - 16.f);
        den += ex;
        num += ex * hs;
    }
    #pragma unroll
    for (int off = 32; off > 0; off >>= 1) {
        den += __shfl_xor(den, off);
        num += __shfl_xor(num, off);
    }
    if (lane == 0) out[nd] = fmaxf(num / (den + 1e-16f) + B, 0.f);
}

// ---------------- launch ----------------
extern "C" void kernel_launch(void* const* d_in, const int* in_sizes, int n_in,
                              void* d_out, int out_size, void* d_ws, size_t ws_size,
                              hipStream_t stream) {
    const int N_ = in_sizes[0] / 128;
    const int E_ = in_sizes[1] / 2;
    const int E2 = E_ + N_;
    const int NB = (N_ + 255) >> 8;

    const float* x = (const float*)d_in[0];
    const int* ei = (const int*)d_in[1];
    const float* W1 = (const float*)d_in[2];
    const float* a1s = (const float*)d_in[3];
    const float* a1d = (const float*)d_in[4];
    const float* b1 = (const float*)d_in[5];
    const float* g1 = (const float*)d_in[6];
    const float* be1 = (const float*)d_in[7];
    const float* W2 = (const float*)d_in[8];
    const float* a2s = (const float*)d_in[9];
    const float* a2d = (const float*)d_in[10];
    const float* b2 = (const float*)d_in[11];
    const float* g2 = (const float*)d_in[12];
    const float* be2 = (const float*)d_in[13];
    const float* W3 = (const float*)d_in[14];
    const float* a3s = (const float*)d_in[15];
    const float* a3d = (const float*)d_in[16];
    const float* b3 = (const float*)d_in[17];
    float* out = (float*)d_out;

    char* p = (char*)d_ws;
    auto alloc = [&](size_t bytes) {
        void* r = (void*)p;
        p += (bytes + 255) & ~(size_t)255;
        return r;
    };
    int* bCnt = (int*)alloc((size_t)NBMAX * 4);
    int* bOff = (int*)alloc((size_t)(NBMAX + 1) * 4);
    int* bFill = (int*)alloc((size_t)NBMAX * 4);
    int* rowptr = (int*)alloc((size_t)(N_ + 1) * 4);
    unsigned int* staging = (unsigned int*)alloc((size_t)E2 * 4);
    int* csr = (int*)alloc((size_t)E2 * 4);
    float* Hb = (float*)alloc((size_t)N_ * 128 * 4);
    float* G = (float*)alloc((size_t)N_ * 128 * 4);
    float* es = (float*)alloc((size_t)N_ * 4 * 4);
    float* ed = (float*)alloc((size_t)N_ * 4 * 4);
    float* h3 = (float*)alloc((size_t)N_ * 4);
    float* bn = (float*)alloc(512 * 4);

    // CSR build
    hipMemsetAsync(bCnt, 0, (size_t)NBMAX * 4, stream);
    k_hist<<<512, 256, 0, stream>>>(ei, bCnt, E_, N_);
    k_bscan<<<1, 256, 0, stream>>>(bCnt, bOff, bFill, rowptr, N_, E2);
    k_partition<<<(E2 + CHUNK - 1) / CHUNK, 256, 0, stream>>>(ei, bFill, staging, E_, N_);
    k_emit<<<NB, 256, 0, stream>>>(staging, bOff, rowptr, csr, N_);

    int gemmB = (N_ + 31) / 32;

    // ----- layer 1 -----
    k_gemm128<<<gemmB, 256, 0, stream>>>(x, W1, Hb, nullptr, nullptr, a1s, a1d, es, ed, N_);
    k_node_gat<<<N_, 128, 0, stream>>>(Hb, es, ed, rowptr, csr, b1, G, N_);
    hipMemsetAsync(bn, 0, 256 * 4, stream);
    k_bn_stats<<<512, 128, 0, stream>>>(G, bn, bn + 128, N_);
    k_bn_finalize<<<1, 128, 0, stream>>>(bn, bn + 128, g1, be1, bn + 256, bn + 384, N_);

    // ----- layer 2 (BN1+ReLU fused into GEMM X-load) -----
    k_gemm128<<<gemmB, 256, 0, stream>>>(G, W2, Hb, bn + 256, bn + 384, a2s, a2d, es, ed, N_);
    k_node_gat<<<N_, 128, 0, stream>>>(Hb, es, ed, rowptr, csr, b2, G, N_);
    hipMemsetAsync(bn, 0, 256 * 4, stream);
    k_bn_stats<<<512, 128, 0, stream>>>(G, bn, bn + 128, N_);
    k_bn_finalize<<<1, 128, 0, stream>>>(bn, bn + 128, g2, be2, bn + 256, bn + 384, N_);

    // ----- layer 3 (BN2+ReLU fused into dot) -----
    k_dot3<<<(N_ + 3) / 4, 256, 0, stream>>>(G, W3, bn + 256, bn + 384, h3, N_);
    k_gat3<<<N_, 64, 0, stream>>>(h3, a3s, a3d, b3, rowptr, csr, out, N_);
}

// Round 4
// 480.795 us; speedup vs baseline: 1.4272x; 1.0118x over previous
//
#include <hip/hip_runtime.h>
#include <math.h>

#define NEG_SLOPE 0.2f
#define NBMAX 256
#define CHUNK 8192
#define DCAP 16384

__device__ __forceinline__ float lrelu(float x) { return x > 0.f ? x : NEG_SLOPE * x; }

// ---------------- CSR build: 2-level bucket counting sort ----------------
__global__ __launch_bounds__(256) void k_hist(const int* __restrict__ ei, int* __restrict__ bCnt,
                                              int E, int n) {
    __shared__ int lh[NBMAX];
    int NB = (n + 255) >> 8;
    for (int i = threadIdx.x; i < NB; i += 256) lh[i] = 0;
    __syncthreads();
    int E2 = E + n;
    for (int e = blockIdx.x * 256 + threadIdx.x; e < E2; e += gridDim.x * 256) {
        int d = (e < E) ? ei[E + e] : (e - E);
        atomicAdd(&lh[d >> 8], 1);
    }
    __syncthreads();
    for (int i = threadIdx.x; i < NB; i += 256)
        if (lh[i]) atomicAdd(&bCnt[i], lh[i]);
}

__global__ __launch_bounds__(256) void k_bscan(const int* __restrict__ bCnt, int* __restrict__ bOff,
                                               int* __restrict__ bFill, int* __restrict__ rowptr,
                                               int n, int E2) {
    int NB = (n + 255) >> 8;
    int tid = threadIdx.x, lane = tid & 63, wid = tid >> 6;
    int v = (tid < NB) ? bCnt[tid] : 0;
    int s = v;
    #pragma unroll
    for (int off = 1; off < 64; off <<= 1) {
        int t = __shfl_up(s, off);
        if (lane >= off) s += t;
    }
    __shared__ int ws[4];
    if (lane == 63) ws[wid] = s;
    __syncthreads();
    if (tid == 0) {
        int c = 0;
        #pragma unroll
        for (int i = 0; i < 4; ++i) { int t = ws[i]; ws[i] = c; c += t; }
    }
    __syncthreads();
    s += ws[wid];
    int excl = s - v;
    if (tid < NB) { bOff[tid] = excl; bFill[tid] = excl; }
    if (tid == NB - 1) bOff[NB] = excl + v;
    if (tid == 0) rowptr[n] = E2;
}

__global__ __launch_bounds__(256) void k_partition(const int* __restrict__ ei, int* __restrict__ bFill,
                                                   unsigned int* __restrict__ staging, int E, int n) {
    __shared__ int lh[NBMAX];
    __shared__ int lbase[NBMAX];
    int NB = (n + 255) >> 8;
    int E2 = E + n;
    int beg = blockIdx.x * CHUNK;
    int end = min(beg + CHUNK, E2);
    for (int i = threadIdx.x; i < NB; i += 256) lh[i] = 0;
    __syncthreads();
    for (int e = beg + threadIdx.x; e < end; e += 256) {
        int d = (e < E) ? ei[E + e] : (e - E);
        atomicAdd(&lh[d >> 8], 1);
    }
    __syncthreads();
    for (int i = threadIdx.x; i < NB; i += 256) {
        int c = lh[i];
        lbase[i] = c ? atomicAdd(&bFill[i], c) : 0;
        lh[i] = 0;
    }
    __syncthreads();
    for (int e = beg + threadIdx.x; e < end; e += 256) {
        int s, d;
        if (e < E) { s = ei[e]; d = ei[E + e]; } else { s = d = e - E; }
        int b = d >> 8;
        int r = atomicAdd(&lh[b], 1);
        staging[lbase[b] + r] = ((unsigned)s << 8) | (unsigned)(d & 255);
    }
}

__global__ __launch_bounds__(256) void k_emit(const unsigned int* __restrict__ staging,
                                              const int* __restrict__ bOff, int* __restrict__ rowptr,
                                              int* __restrict__ csr, int n) {
    __shared__ int lcnt[NBMAX];
    __shared__ int lscan[NBMAX];
    __shared__ int ws[4];
    __shared__ int sorted[DCAP];  // 64 KB
    int b = blockIdx.x;
    int gbase = b << 8;
    int beg = bOff[b], end = bOff[b + 1], m = end - beg;
    int tid = threadIdx.x, lane = tid & 63, wid = tid >> 6;

    lcnt[tid] = 0;
    __syncthreads();
    for (int j = tid; j < m; j += 256) atomicAdd(&lcnt[staging[beg + j] & 255], 1);
    __syncthreads();
    int v = lcnt[tid];
    int s = v;
    #pragma unroll
    for (int off = 1; off < 64; off <<= 1) {
        int t = __shfl_up(s, off);
        if (lane >= off) s += t;
    }
    if (lane == 63) ws[wid] = s;
    __syncthreads();
    if (tid == 0) {
        int c = 0;
        #pragma unroll
        for (int i = 0; i < 4; ++i) { int t = ws[i]; ws[i] = c; c += t; }
    }
    __syncthreads();
    int excl = s + ws[wid] - v;
    lscan[tid] = excl;
    lcnt[tid] = 0;
    __syncthreads();

    if (gbase + tid < n) rowptr[gbase + tid] = beg + lscan[tid];

    if (m <= DCAP) {
        for (int j = tid; j < m; j += 256) {
            unsigned e = staging[beg + j];
            int ld = e & 255;
            int src = e >> 8;
            int r = atomicAdd(&lcnt[ld], 1);
            sorted[lscan[ld] + r] = src;
        }
        __syncthreads();
        for (int j = tid; j < m; j += 256) csr[beg + j] = sorted[j];
    } else {
        for (int j = tid; j < m; j += 256) {
            unsigned e = staging[beg + j];
            int ld = e & 255;
            int src = e >> 8;
            int r = atomicAdd(&lcnt[ld], 1);
            csr[beg + lscan[ld] + r] = src;
        }
    }
}

// ---------------- GEMM: H = relu(X*scale+shift) @ W, fused es/ed epilogue ----------------
__global__ __launch_bounds__(256) void k_gemm128(const float* __restrict__ X, const float* __restrict__ W,
                                                 float* __restrict__ Hout,
                                                 const float* __restrict__ scale, const float* __restrict__ shift,
                                                 const float* __restrict__ as_f, const float* __restrict__ ad_f,
                                                 float* __restrict__ es, float* __restrict__ ed, int n) {
    __shared__ float Wl[64 * 128];  // 32 KB
    __shared__ float Xl[64 * 32];   // 8 KB, swizzled
    int tid = threadIdx.x;
    int row0 = blockIdx.x * 32;
    int cg = tid & 31, ng = tid >> 5;
    int c0 = cg * 4, r0 = ng * 4;
    float acc[4][4] = {{0.f}};
    for (int kb = 0; kb < 128; kb += 64) {
        const float4* Wg = (const float4*)(W + (size_t)kb * 128);
        float4* Wl4 = (float4*)Wl;
        #pragma unroll
        for (int j = 0; j < 8; ++j) Wl4[tid + j * 256] = Wg[tid + j * 256];
        #pragma unroll
        for (int j = 0; j < 2; ++j) {
            int idx = tid + j * 256;
            int r = idx >> 4;
            int k4 = idx & 15;
            float4 v = make_float4(0.f, 0.f, 0.f, 0.f);
            if (row0 + r < n) v = ((const float4*)(X + (size_t)(row0 + r) * 128 + kb))[k4];
            if (scale) {
                int kc = kb + k4 * 4;
                float4 sc = *(const float4*)&scale[kc];
                float4 sh = *(const float4*)&shift[kc];
                v.x = fmaxf(v.x * sc.x + sh.x, 0.f);
                v.y = fmaxf(v.y * sc.y + sh.y, 0.f);
                v.z = fmaxf(v.z * sc.z + sh.z, 0.f);
                v.w = fmaxf(v.w * sc.w + sh.w, 0.f);
            }
            int k = k4 * 4;
            Xl[(k + 0) * 32 + (r ^ ((k + 0) & 31))] = v.x;
            Xl[(k + 1) * 32 + (r ^ ((k + 1) & 31))] = v.y;
            Xl[(k + 2) * 32 + (r ^ ((k + 2) & 31))] = v.z;
            Xl[(k + 3) * 32 + (r ^ ((k + 3) & 31))] = v.w;
        }
        __syncthreads();
        #pragma unroll
        for (int k = 0; k < 64; ++k) {
            float4 wv = *(const float4*)&Wl[k * 128 + c0];
            float x0 = Xl[k * 32 + ((r0 + 0) ^ (k & 31))];
            float x1 = Xl[k * 32 + ((r0 + 1) ^ (k & 31))];
            float x2 = Xl[k * 32 + ((r0 + 2) ^ (k & 31))];
            float x3 = Xl[k * 32 + ((r0 + 3) ^ (k & 31))];
            acc[0][0] += x0 * wv.x; acc[0][1] += x0 * wv.y; acc[0][2] += x0 * wv.z; acc[0][3] += x0 * wv.w;
            acc[1][0] += x1 * wv.x; acc[1][1] += x1 * wv.y; acc[1][2] += x1 * wv.z; acc[1][3] += x1 * wv.w;
            acc[2][0] += x2 * wv.x; acc[2][1] += x2 * wv.y; acc[2][2] += x2 * wv.z; acc[2][3] += x2 * wv.w;
            acc[3][0] += x3 * wv.x; acc[3][1] += x3 * wv.y; acc[3][2] += x3 * wv.z; acc[3][3] += x3 * wv.w;
        }
        __syncthreads();
    }
    #pragma unroll
    for (int i = 0; i < 4; ++i) {
        int r = row0 + r0 + i;
        if (r < n)
            *(float4*)&Hout[(size_t)r * 128 + c0] =
                make_float4(acc[i][0], acc[i][1], acc[i][2], acc[i][3]);
    }
    // fused attention-score epilogue
    float4 asv = *(const float4*)&as_f[c0];
    float4 adv = *(const float4*)&ad_f[c0];
    float ps[4], pd[4];
    #pragma unroll
    for (int i = 0; i < 4; ++i) {
        ps[i] = acc[i][0] * asv.x + acc[i][1] * asv.y + acc[i][2] * asv.z + acc[i][3] * asv.w;
        pd[i] = acc[i][0] * adv.x + acc[i][1] * adv.y + acc[i][2] * adv.z + acc[i][3] * adv.w;
    }
    #pragma unroll
    for (int off = 1; off <= 4; off <<= 1) {
        #pragma unroll
        for (int i = 0; i < 4; ++i) {
            ps[i] += __shfl_xor(ps[i], off);
            pd[i] += __shfl_xor(pd[i], off);
        }
    }
    if ((cg & 7) == 0) {
        int hh = cg >> 3;
        #pragma unroll
        for (int i = 0; i < 4; ++i) {
            int r = row0 + r0 + i;
            if (r < n) {
                es[(size_t)r * 4 + hh] = ps[i];
                ed[(size_t)r * 4 + hh] = pd[i];
            }
        }
    }
}

// ---------------- per-node GAT: barrier-free inline-weight gather ----------------
// 128 thr = 4 edge-slots x 32 channel-lanes. Per slot, csr/es loads are
// same-address (HW broadcast); each lane computes its own head's weight
// inline (exp redundancy is free, VALU was 75% idle). No LDS staging, no
// barriers in the loop -> deep vmcnt pipelining of independent iterations.
__global__ __launch_bounds__(128) void k_node_gat(
    const float* __restrict__ Hf, const float* __restrict__ es, const float* __restrict__ ed,
    const int* __restrict__ ptr, const int* __restrict__ csr,
    const float* __restrict__ bias, float* __restrict__ out, int n) {
    int nd = blockIdx.x;
    if (nd >= n) return;
    int tid = threadIdx.x;
    int cg = tid & 31;    // float4 channel group (0..31)
    int slot = tid >> 5;  // edge slot 0..3
    int hh = cg >> 3;     // head of my channels
    int beg = ptr[nd], deg = ptr[nd + 1] - beg;

    __shared__ float accred[4][32];
    __shared__ float dred[32];

    float edn = ed[(size_t)nd * 4 + hh];
    const float4* H4 = (const float4*)Hf;

    float4 acc = make_float4(0.f, 0.f, 0.f, 0.f);
    float den = 0.f;

    int i = slot;
    for (; i + 4 < deg; i += 8) {
        int s0 = csr[beg + i];
        int s1 = csr[beg + i + 4];
        float e0 = es[(size_t)s0 * 4 + hh];
        float e1 = es[(size_t)s1 * 4 + hh];
        float4 h0 = H4[(size_t)s0 * 32 + cg];
        float4 h1 = H4[(size_t)s1 * 32 + cg];
        float w0 = __expf(lrelu(e0 + edn) - 16.f);
        float w1 = __expf(lrelu(e1 + edn) - 16.f);
        den += w0 + w1;
        acc.x += w0 * h0.x + w1 * h1.x;
        acc.y += w0 * h0.y + w1 * h1.y;
        acc.z += w0 * h0.z + w1 * h1.z;
        acc.w += w0 * h0.w + w1 * h1.w;
    }
    if (i < deg) {
        int s0 = csr[beg + i];
        float e0 = es[(size_t)s0 * 4 + hh];
        float4 h0 = H4[(size_t)s0 * 32 + cg];
        float w0 = __expf(lrelu(e0 + edn) - 16.f);
        den += w0;
        acc.x += w0 * h0.x;
        acc.y += w0 * h0.y;
        acc.z += w0 * h0.z;
        acc.w += w0 * h0.w;
    }

    // combine slot pairs within wave (lanes l and l+32 hold slots 2k,2k+1)
    acc.x += __shfl_xor(acc.x, 32);
    acc.y += __shfl_xor(acc.y, 32);
    acc.z += __shfl_xor(acc.z, 32);
    acc.w += __shfl_xor(acc.w, 32);
    den += __shfl_xor(den, 32);

    // cross-wave: wave1 publishes, wave0 finishes
    if (tid >= 64 && tid < 96) {
        accred[0][cg] = acc.x;
        accred[1][cg] = acc.y;
        accred[2][cg] = acc.z;
        accred[3][cg] = acc.w;
        dred[cg] = den;
    }
    __syncthreads();
    if (tid < 32) {
        acc.x += accred[0][tid];
        acc.y += accred[1][tid];
        acc.z += accred[2][tid];
        acc.w += accred[3][tid];
        den += dred[tid];
        float inv = 1.f / (den + 1e-16f);
        float4 bv = *(const float4*)&bias[tid * 4];
        float4 o = make_float4(acc.x * inv + bv.x, acc.y * inv + bv.y,
                               acc.z * inv + bv.z, acc.w * inv + bv.w);
        *(float4*)&out[(size_t)nd * 128 + tid * 4] = o;
    }
}

// ---------------- batch norm stats ----------------
__global__ __launch_bounds__(128) void k_bn_stats(const float* __restrict__ G, float* __restrict__ sum,
                                                  float* __restrict__ sumsq, int n) {
    int c = threadIdx.x;
    float s = 0.f, s2 = 0.f;
    for (int r = blockIdx.x; r < n; r += gridDim.x) {
        float v = G[(size_t)r * 128 + c];
        s += v;
        s2 += v * v;
    }
    atomicAdd(&sum[c], s);
    atomicAdd(&sumsq[c], s2);
}

__global__ void k_bn_finalize(const float* __restrict__ sum, const float* __restrict__ sumsq,
                              const float* __restrict__ g, const float* __restrict__ be,
                              float* __restrict__ scale, float* __restrict__ shift, int n) {
    int c = threadIdx.x;  // 128
    float mean = sum[c] / (float)n;
    float var = sumsq[c] / (float)n - mean * mean;
    float sc = g[c] * rsqrtf(var + 1e-5f);
    scale[c] = sc;
    shift[c] = be[c] - mean * sc;
}

// ---------------- layer 3 (BN+ReLU fused into dot) ----------------
__global__ __launch_bounds__(256) void k_dot3(const float* __restrict__ F, const float* __restrict__ W3,
                                              const float* __restrict__ scale, const float* __restrict__ shift,
                                              float* __restrict__ h3, int n) {
    int wid = threadIdx.x >> 6, lane = threadIdx.x & 63;
    int nd = blockIdx.x * 4 + wid;
    if (nd >= n) return;
    const float* row = F + (size_t)nd * 128;
    float v0 = fmaxf(row[lane] * scale[lane] + shift[lane], 0.f);
    float v1 = fmaxf(row[lane + 64] * scale[lane + 64] + shift[lane + 64], 0.f);
    float v = v0 * W3[lane] + v1 * W3[lane + 64];
    #pragma unroll
    for (int off = 32; off > 0; off >>= 1) v += __shfl_xor(v, off);
    if (lane == 0) h3[nd] = v;
}

__global__ __launch_bounds__(64) void k_gat3(const float* __restrict__ h3, const float* __restrict__ a3s,
                                             const float* __restrict__ a3d, const float* __restrict__ b3,
                                             const int* __restrict__ ptr, const int* __restrict__ csr,
                                             float* __restrict__ out, int n) {
    int nd = blockIdx.x;
    if (nd >= n) return;
    int lane = threadIdx.x;
    int beg = ptr[nd], deg = ptr[nd + 1] - beg;
    float As = a3s[0], Ad = a3d[0], B = b3[0];
    float hd = h3[nd] * Ad;
    float den = 0.f, num = 0.f;
    for (int i = lane; i < deg; i += 64) {
        float hs = h3[csr[beg + i]];
        float a = lrelu(hs * As + hd);
        float ex = __expf(a - 16.f);
        den += ex;
        num += ex * hs;
    }
    #pragma unroll
    for (int off = 32; off > 0; off >>= 1) {
        den += __shfl_xor(den, off);
        num += __shfl_xor(num, off);
    }
    if (lane == 0) out[nd] = fmaxf(num / (den + 1e-16f) + B, 0.f);
}

// ---------------- launch ----------------
extern "C" void kernel_launch(void* const* d_in, const int* in_sizes, int n_in,
                              void* d_out, int out_size, void* d_ws, size_t ws_size,
                              hipStream_t stream) {
    const int N_ = in_sizes[0] / 128;
    const int E_ = in_sizes[1] / 2;
    const int E2 = E_ + N_;
    const int NB = (N_ + 255) >> 8;

    const float* x = (const float*)d_in[0];
    const int* ei = (const int*)d_in[1];
    const float* W1 = (const float*)d_in[2];
    const float* a1s = (const float*)d_in[3];
    const float* a1d = (const float*)d_in[4];
    const float* b1 = (const float*)d_in[5];
    const float* g1 = (const float*)d_in[6];
    const float* be1 = (const float*)d_in[7];
    const float* W2 = (const float*)d_in[8];
    const float* a2s = (const float*)d_in[9];
    const float* a2d = (const float*)d_in[10];
    const float* b2 = (const float*)d_in[11];
    const float* g2 = (const float*)d_in[12];
    const float* be2 = (const float*)d_in[13];
    const float* W3 = (const float*)d_in[14];
    const float* a3s = (const float*)d_in[15];
    const float* a3d = (const float*)d_in[16];
    const float* b3 = (const float*)d_in[17];
    float* out = (float*)d_out;

    char* p = (char*)d_ws;
    auto alloc = [&](size_t bytes) {
        void* r = (void*)p;
        p += (bytes + 255) & ~(size_t)255;
        return r;
    };
    int* bCnt = (int*)alloc((size_t)NBMAX * 4);
    int* bOff = (int*)alloc((size_t)(NBMAX + 1) * 4);
    int* bFill = (int*)alloc((size_t)NBMAX * 4);
    int* rowptr = (int*)alloc((size_t)(N_ + 1) * 4);
    unsigned int* staging = (unsigned int*)alloc((size_t)E2 * 4);
    int* csr = (int*)alloc((size_t)E2 * 4);
    float* Hb = (float*)alloc((size_t)N_ * 128 * 4);
    float* G = (float*)alloc((size_t)N_ * 128 * 4);
    float* es = (float*)alloc((size_t)N_ * 4 * 4);
    float* ed = (float*)alloc((size_t)N_ * 4 * 4);
    float* h3 = (float*)alloc((size_t)N_ * 4);
    float* bn = (float*)alloc(512 * 4);

    // CSR build
    hipMemsetAsync(bCnt, 0, (size_t)NBMAX * 4, stream);
    k_hist<<<512, 256, 0, stream>>>(ei, bCnt, E_, N_);
    k_bscan<<<1, 256, 0, stream>>>(bCnt, bOff, bFill, rowptr, N_, E2);
    k_partition<<<(E2 + CHUNK - 1) / CHUNK, 256, 0, stream>>>(ei, bFill, staging, E_, N_);
    k_emit<<<NB, 256, 0, stream>>>(staging, bOff, rowptr, csr, N_);

    int gemmB = (N_ + 31) / 32;

    // ----- layer 1 -----
    k_gemm128<<<gemmB, 256, 0, stream>>>(x, W1, Hb, nullptr, nullptr, a1s, a1d, es, ed, N_);
    k_node_gat<<<N_, 128, 0, stream>>>(Hb, es, ed, rowptr, csr, b1, G, N_);
    hipMemsetAsync(bn, 0, 256 * 4, stream);
    k_bn_stats<<<512, 128, 0, stream>>>(G, bn, bn + 128, N_);
    k_bn_finalize<<<1, 128, 0, stream>>>(bn, bn + 128, g1, be1, bn + 256, bn + 384, N_);

    // ----- layer 2 (BN1+ReLU fused into GEMM X-load) -----
    k_gemm128<<<gemmB, 256, 0, stream>>>(G, W2, Hb, bn + 256, bn + 384, a2s, a2d, es, ed, N_);
    k_node_gat<<<N_, 128, 0, stream>>>(Hb, es, ed, rowptr, csr, b2, G, N_);
    hipMemsetAsync(bn, 0, 256 * 4, stream);
    k_bn_stats<<<512, 128, 0, stream>>>(G, bn, bn + 128, N_);
    k_bn_finalize<<<1, 128, 0, stream>>>(bn, bn + 128, g2, be2, bn + 256, bn + 384, N_);

    // ----- layer 3 (BN2+ReLU fused into dot) -----
    k_dot3<<<(N_ + 3) / 4, 256, 0, stream>>>(G, W3, bn + 256, bn + 384, h3, N_);
    k_gat3<<<N_, 64, 0, stream>>>(h3, a3s, a3d, b3, rowptr, csr, out, N_);
}

// Round 5
// 390.441 us; speedup vs baseline: 1.7575x; 1.2314x over previous
//
#include <hip/hip_runtime.h>
#include <math.h>

#define NEG_SLOPE 0.2f
#define NBMAX 256
#define CHUNK 8192
#define DCAP 16384

__device__ __forceinline__ float lrelu(float x) { return x > 0.f ? x : NEG_SLOPE * x; }

__device__ __forceinline__ unsigned short f2bf(float f) {
    unsigned u = __float_as_uint(f);
    return (unsigned short)((u + 0x7fffu + ((u >> 16) & 1u)) >> 16);
}
__device__ __forceinline__ float bf2f(unsigned short b) {
    return __uint_as_float((unsigned)b << 16);
}

// ---------------- CSR build: 2-level bucket counting sort ----------------
__global__ __launch_bounds__(256) void k_hist(const int* __restrict__ ei, int* __restrict__ bCnt,
                                              int E, int n) {
    __shared__ int lh[NBMAX];
    int NB = (n + 255) >> 8;
    for (int i = threadIdx.x; i < NB; i += 256) lh[i] = 0;
    __syncthreads();
    int E2 = E + n;
    for (int e = blockIdx.x * 256 + threadIdx.x; e < E2; e += gridDim.x * 256) {
        int d = (e < E) ? ei[E + e] : (e - E);
        atomicAdd(&lh[d >> 8], 1);
    }
    __syncthreads();
    for (int i = threadIdx.x; i < NB; i += 256)
        if (lh[i]) atomicAdd(&bCnt[i], lh[i]);
}

__global__ __launch_bounds__(256) void k_bscan(const int* __restrict__ bCnt, int* __restrict__ bOff,
                                               int* __restrict__ bFill, int* __restrict__ rowptr,
                                               int n, int E2) {
    int NB = (n + 255) >> 8;
    int tid = threadIdx.x, lane = tid & 63, wid = tid >> 6;
    int v = (tid < NB) ? bCnt[tid] : 0;
    int s = v;
    #pragma unroll
    for (int off = 1; off < 64; off <<= 1) {
        int t = __shfl_up(s, off);
        if (lane >= off) s += t;
    }
    __shared__ int ws[4];
    if (lane == 63) ws[wid] = s;
    __syncthreads();
    if (tid == 0) {
        int c = 0;
        #pragma unroll
        for (int i = 0; i < 4; ++i) { int t = ws[i]; ws[i] = c; c += t; }
    }
    __syncthreads();
    s += ws[wid];
    int excl = s - v;
    if (tid < NB) { bOff[tid] = excl; bFill[tid] = excl; }
    if (tid == NB - 1) bOff[NB] = excl + v;
    if (tid == 0) rowptr[n] = E2;
}

__global__ __launch_bounds__(256) void k_partition(const int* __restrict__ ei, int* __restrict__ bFill,
                                                   unsigned int* __restrict__ staging, int E, int n) {
    __shared__ int lh[NBMAX];
    __shared__ int lbase[NBMAX];
    int NB = (n + 255) >> 8;
    int E2 = E + n;
    int beg = blockIdx.x * CHUNK;
    int end = min(beg + CHUNK, E2);
    for (int i = threadIdx.x; i < NB; i += 256) lh[i] = 0;
    __syncthreads();
    for (int e = beg + threadIdx.x; e < end; e += 256) {
        int d = (e < E) ? ei[E + e] : (e - E);
        atomicAdd(&lh[d >> 8], 1);
    }
    __syncthreads();
    for (int i = threadIdx.x; i < NB; i += 256) {
        int c = lh[i];
        lbase[i] = c ? atomicAdd(&bFill[i], c) : 0;
        lh[i] = 0;
    }
    __syncthreads();
    for (int e = beg + threadIdx.x; e < end; e += 256) {
        int s, d;
        if (e < E) { s = ei[e]; d = ei[E + e]; } else { s = d = e - E; }
        int b = d >> 8;
        int r = atomicAdd(&lh[b], 1);
        staging[lbase[b] + r] = ((unsigned)s << 8) | (unsigned)(d & 255);
    }
}

__global__ __launch_bounds__(256) void k_emit(const unsigned int* __restrict__ staging,
                                              const int* __restrict__ bOff, int* __restrict__ rowptr,
                                              int* __restrict__ csr, int n) {
    __shared__ int lcnt[NBMAX];
    __shared__ int lscan[NBMAX];
    __shared__ int ws[4];
    __shared__ int sorted[DCAP];  // 64 KB
    int b = blockIdx.x;
    int gbase = b << 8;
    int beg = bOff[b], end = bOff[b + 1], m = end - beg;
    int tid = threadIdx.x, lane = tid & 63, wid = tid >> 6;

    lcnt[tid] = 0;
    __syncthreads();
    for (int j = tid; j < m; j += 256) atomicAdd(&lcnt[staging[beg + j] & 255], 1);
    __syncthreads();
    int v = lcnt[tid];
    int s = v;
    #pragma unroll
    for (int off = 1; off < 64; off <<= 1) {
        int t = __shfl_up(s, off);
        if (lane >= off) s += t;
    }
    if (lane == 63) ws[wid] = s;
    __syncthreads();
    if (tid == 0) {
        int c = 0;
        #pragma unroll
        for (int i = 0; i < 4; ++i) { int t = ws[i]; ws[i] = c; c += t; }
    }
    __syncthreads();
    int excl = s + ws[wid] - v;
    lscan[tid] = excl;
    lcnt[tid] = 0;
    __syncthreads();

    if (gbase + tid < n) rowptr[gbase + tid] = beg + lscan[tid];

    if (m <= DCAP) {
        for (int j = tid; j < m; j += 256) {
            unsigned e = staging[beg + j];
            int ld = e & 255;
            int src = e >> 8;
            int r = atomicAdd(&lcnt[ld], 1);
            sorted[lscan[ld] + r] = src;
        }
        __syncthreads();
        for (int j = tid; j < m; j += 256) csr[beg + j] = sorted[j];
    } else {
        for (int j = tid; j < m; j += 256) {
            unsigned e = staging[beg + j];
            int ld = e & 255;
            int src = e >> 8;
            int r = atomicAdd(&lcnt[ld], 1);
            csr[beg + lscan[ld] + r] = src;
        }
    }
}

// ---------------- GEMM: H(bf16) = relu(X*scale+shift) @ W, fused es/ed epilogue ----------------
__global__ __launch_bounds__(256) void k_gemm128(const float* __restrict__ X, const float* __restrict__ W,
                                                 unsigned short* __restrict__ Hout,
                                                 const float* __restrict__ scale, const float* __restrict__ shift,
                                                 const float* __restrict__ as_f, const float* __restrict__ ad_f,
                                                 float* __restrict__ es, float* __restrict__ ed, int n) {
    __shared__ float Wl[64 * 128];  // 32 KB
    __shared__ float Xl[64 * 32];   // 8 KB, swizzled
    int tid = threadIdx.x;
    int row0 = blockIdx.x * 32;
    int cg = tid & 31, ng = tid >> 5;
    int c0 = cg * 4, r0 = ng * 4;
    float acc[4][4] = {{0.f}};
    for (int kb = 0; kb < 128; kb += 64) {
        const float4* Wg = (const float4*)(W + (size_t)kb * 128);
        float4* Wl4 = (float4*)Wl;
        #pragma unroll
        for (int j = 0; j < 8; ++j) Wl4[tid + j * 256] = Wg[tid + j * 256];
        #pragma unroll
        for (int j = 0; j < 2; ++j) {
            int idx = tid + j * 256;
            int r = idx >> 4;
            int k4 = idx & 15;
            float4 v = make_float4(0.f, 0.f, 0.f, 0.f);
            if (row0 + r < n) v = ((const float4*)(X + (size_t)(row0 + r) * 128 + kb))[k4];
            if (scale) {
                int kc = kb + k4 * 4;
                float4 sc = *(const float4*)&scale[kc];
                float4 sh = *(const float4*)&shift[kc];
                v.x = fmaxf(v.x * sc.x + sh.x, 0.f);
                v.y = fmaxf(v.y * sc.y + sh.y, 0.f);
                v.z = fmaxf(v.z * sc.z + sh.z, 0.f);
                v.w = fmaxf(v.w * sc.w + sh.w, 0.f);
            }
            int k = k4 * 4;
            Xl[(k + 0) * 32 + (r ^ ((k + 0) & 31))] = v.x;
            Xl[(k + 1) * 32 + (r ^ ((k + 1) & 31))] = v.y;
            Xl[(k + 2) * 32 + (r ^ ((k + 2) & 31))] = v.z;
            Xl[(k + 3) * 32 + (r ^ ((k + 3) & 31))] = v.w;
        }
        __syncthreads();
        #pragma unroll
        for (int k = 0; k < 64; ++k) {
            float4 wv = *(const float4*)&Wl[k * 128 + c0];
            float x0 = Xl[k * 32 + ((r0 + 0) ^ (k & 31))];
            float x1 = Xl[k * 32 + ((r0 + 1) ^ (k & 31))];
            float x2 = Xl[k * 32 + ((r0 + 2) ^ (k & 31))];
            float x3 = Xl[k * 32 + ((r0 + 3) ^ (k & 31))];
            acc[0][0] += x0 * wv.x; acc[0][1] += x0 * wv.y; acc[0][2] += x0 * wv.z; acc[0][3] += x0 * wv.w;
            acc[1][0] += x1 * wv.x; acc[1][1] += x1 * wv.y; acc[1][2] += x1 * wv.z; acc[1][3] += x1 * wv.w;
            acc[2][0] += x2 * wv.x; acc[2][1] += x2 * wv.y; acc[2][2] += x2 * wv.z; acc[2][3] += x2 * wv.w;
            acc[3][0] += x3 * wv.x; acc[3][1] += x3 * wv.y; acc[3][2] += x3 * wv.z; acc[3][3] += x3 * wv.w;
        }
        __syncthreads();
    }
    #pragma unroll
    for (int i = 0; i < 4; ++i) {
        int r = row0 + r0 + i;
        if (r < n) {
            ushort4 o;
            o.x = f2bf(acc[i][0]);
            o.y = f2bf(acc[i][1]);
            o.z = f2bf(acc[i][2]);
            o.w = f2bf(acc[i][3]);
            *(ushort4*)&Hout[(size_t)r * 128 + c0] = o;
        }
    }
    // fused attention-score epilogue (fp32 acc -> exact es/ed)
    float4 asv = *(const float4*)&as_f[c0];
    float4 adv = *(const float4*)&ad_f[c0];
    float ps[4], pd[4];
    #pragma unroll
    for (int i = 0; i < 4; ++i) {
        ps[i] = acc[i][0] * asv.x + acc[i][1] * asv.y + acc[i][2] * asv.z + acc[i][3] * asv.w;
        pd[i] = acc[i][0] * adv.x + acc[i][1] * adv.y + acc[i][2] * adv.z + acc[i][3] * adv.w;
    }
    #pragma unroll
    for (int off = 1; off <= 4; off <<= 1) {
        #pragma unroll
        for (int i = 0; i < 4; ++i) {
            ps[i] += __shfl_xor(ps[i], off);
            pd[i] += __shfl_xor(pd[i], off);
        }
    }
    if ((cg & 7) == 0) {
        int hh = cg >> 3;
        #pragma unroll
        for (int i = 0; i < 4; ++i) {
            int r = row0 + r0 + i;
            if (r < n) {
                es[(size_t)r * 4 + hh] = ps[i];
                ed[(size_t)r * 4 + hh] = pd[i];
            }
        }
    }
}

// ---------------- per-node GAT: bf16 H gather, barrier-free ----------------
__global__ __launch_bounds__(128) void k_node_gat(
    const unsigned short* __restrict__ Hf, const float* __restrict__ es, const float* __restrict__ ed,
    const int* __restrict__ ptr, const int* __restrict__ csr,
    const float* __restrict__ bias, float* __restrict__ out, int n) {
    int nd = blockIdx.x;
    if (nd >= n) return;
    int tid = threadIdx.x;
    int cg = tid & 31;    // channel group (4 ch each)
    int slot = tid >> 5;  // edge slot 0..3
    int hh = cg >> 3;     // head of my channels
    int beg = ptr[nd], deg = ptr[nd + 1] - beg;

    __shared__ float accred[4][32];
    __shared__ float dred[32];

    float edn = ed[(size_t)nd * 4 + hh];
    const ushort4* H2 = (const ushort4*)Hf;  // row stride = 32 ushort4

    float4 acc = make_float4(0.f, 0.f, 0.f, 0.f);
    float den = 0.f;

    int i = slot;
    for (; i + 4 < deg; i += 8) {
        int s0 = csr[beg + i];
        int s1 = csr[beg + i + 4];
        float e0 = es[(size_t)s0 * 4 + hh];
        float e1 = es[(size_t)s1 * 4 + hh];
        ushort4 p0 = H2[(size_t)s0 * 32 + cg];
        ushort4 p1 = H2[(size_t)s1 * 32 + cg];
        float w0 = __expf(lrelu(e0 + edn) - 16.f);
        float w1 = __expf(lrelu(e1 + edn) - 16.f);
        den += w0 + w1;
        acc.x += w0 * bf2f(p0.x) + w1 * bf2f(p1.x);
        acc.y += w0 * bf2f(p0.y) + w1 * bf2f(p1.y);
        acc.z += w0 * bf2f(p0.z) + w1 * bf2f(p1.z);
        acc.w += w0 * bf2f(p0.w) + w1 * bf2f(p1.w);
    }
    if (i < deg) {
        int s0 = csr[beg + i];
        float e0 = es[(size_t)s0 * 4 + hh];
        ushort4 p0 = H2[(size_t)s0 * 32 + cg];
        float w0 = __expf(lrelu(e0 + edn) - 16.f);
        den += w0;
        acc.x += w0 * bf2f(p0.x);
        acc.y += w0 * bf2f(p0.y);
        acc.z += w0 * bf2f(p0.z);
        acc.w += w0 * bf2f(p0.w);
    }

    // combine slot pairs within wave
    acc.x += __shfl_xor(acc.x, 32);
    acc.y += __shfl_xor(acc.y, 32);
    acc.z += __shfl_xor(acc.z, 32);
    acc.w += __shfl_xor(acc.w, 32);
    den += __shfl_xor(den, 32);

    if (tid >= 64 && tid < 96) {
        accred[0][cg] = acc.x;
        accred[1][cg] = acc.y;
        accred[2][cg] = acc.z;
        accred[3][cg] = acc.w;
        dred[cg] = den;
    }
    __syncthreads();
    if (tid < 32) {
        acc.x += accred[0][tid];
        acc.y += accred[1][tid];
        acc.z += accred[2][tid];
        acc.w += accred[3][tid];
        den += dred[tid];
        float inv = 1.f / (den + 1e-16f);
        float4 bv = *(const float4*)&bias[tid * 4];
        float4 o = make_float4(acc.x * inv + bv.x, acc.y * inv + bv.y,
                               acc.z * inv + bv.z, acc.w * inv + bv.w);
        *(float4*)&out[(size_t)nd * 128 + tid * 4] = o;
    }
}

// ---------------- batch norm stats ----------------
__global__ __launch_bounds__(128) void k_bn_stats(const float* __restrict__ G, float* __restrict__ sum,
                                                  float* __restrict__ sumsq, int n) {
    int c = threadIdx.x;
    float s = 0.f, s2 = 0.f;
    for (int r = blockIdx.x; r < n; r += gridDim.x) {
        float v = G[(size_t)r * 128 + c];
        s += v;
        s2 += v * v;
    }
    atomicAdd(&sum[c], s);
    atomicAdd(&sumsq[c], s2);
}

__global__ void k_bn_finalize(const float* __restrict__ sum, const float* __restrict__ sumsq,
                              const float* __restrict__ g, const float* __restrict__ be,
                              float* __restrict__ scale, float* __restrict__ shift, int n) {
    int c = threadIdx.x;  // 128
    float mean = sum[c] / (float)n;
    float var = sumsq[c] / (float)n - mean * mean;
    float sc = g[c] * rsqrtf(var + 1e-5f);
    scale[c] = sc;
    shift[c] = be[c] - mean * sc;
}

// ---------------- layer 3 (BN+ReLU fused into dot) ----------------
__global__ __launch_bounds__(256) void k_dot3(const float* __restrict__ F, const float* __restrict__ W3,
                                              const float* __restrict__ scale, const float* __restrict__ shift,
                                              float* __restrict__ h3, int n) {
    int wid = threadIdx.x >> 6, lane = threadIdx.x & 63;
    int nd = blockIdx.x * 4 + wid;
    if (nd >= n) return;
    const float* row = F + (size_t)nd * 128;
    float v0 = fmaxf(row[lane] * scale[lane] + shift[lane], 0.f);
    float v1 = fmaxf(row[lane + 64] * scale[lane + 64] + shift[lane + 64], 0.f);
    float v = v0 * W3[lane] + v1 * W3[lane + 64];
    #pragma unroll
    for (int off = 32; off > 0; off >>= 1) v += __shfl_xor(v, off);
    if (lane == 0) h3[nd] = v;
}

__global__ __launch_bounds__(64) void k_gat3(const float* __restrict__ h3, const float* __restrict__ a3s,
                                             const float* __restrict__ a3d, const float* __restrict__ b3,
                                             const int* __restrict__ ptr, const int* __restrict__ csr,
                                             float* __restrict__ out, int n) {
    int nd = blockIdx.x;
    if (nd >= n) return;
    int lane = threadIdx.x;
    int beg = ptr[nd], deg = ptr[nd + 1] - beg;
    float As = a3s[0], Ad = a3d[0], B = b3[0];
    float hd = h3[nd] * Ad;
    float den = 0.f, num = 0.f;
    for (int i = lane; i < deg; i += 64) {
        float hs = h3[csr[beg + i]];
        float a = lrelu(hs * As + hd);
        float ex = __expf(a - 16.f);
        den += ex;
        num += ex * hs;
    }
    #pragma unroll
    for (int off = 32; off > 0; off >>= 1) {
        den += __shfl_xor(den, off);
        num += __shfl_xor(num, off);
    }
    if (lane == 0) out[nd] = fmaxf(num / (den + 1e-16f) + B, 0.f);
}

// ---------------- launch ----------------
extern "C" void kernel_launch(void* const* d_in, const int* in_sizes, int n_in,
                              void* d_out, int out_size, void* d_ws, size_t ws_size,
                              hipStream_t stream) {
    const int N_ = in_sizes[0] / 128;
    const int E_ = in_sizes[1] / 2;
    const int E2 = E_ + N_;
    const int NB = (N_ + 255) >> 8;

    const float* x = (const float*)d_in[0];
    const int* ei = (const int*)d_in[1];
    const float* W1 = (const float*)d_in[2];
    const float* a1s = (const float*)d_in[3];
    const float* a1d = (const float*)d_in[4];
    const float* b1 = (const float*)d_in[5];
    const float* g1 = (const float*)d_in[6];
    const float* be1 = (const float*)d_in[7];
    const float* W2 = (const float*)d_in[8];
    const float* a2s = (const float*)d_in[9];
    const float* a2d = (const float*)d_in[10];
    const float* b2 = (const float*)d_in[11];
    const float* g2 = (const float*)d_in[12];
    const float* be2 = (const float*)d_in[13];
    const float* W3 = (const float*)d_in[14];
    const float* a3s = (const float*)d_in[15];
    const float* a3d = (const float*)d_in[16];
    const float* b3 = (const float*)d_in[17];
    float* out = (float*)d_out;

    char* p = (char*)d_ws;
    auto alloc = [&](size_t bytes) {
        void* r = (void*)p;
        p += (bytes + 255) & ~(size_t)255;
        return r;
    };
    int* bCnt = (int*)alloc((size_t)NBMAX * 4);
    int* bOff = (int*)alloc((size_t)(NBMAX + 1) * 4);
    int* bFill = (int*)alloc((size_t)NBMAX * 4);
    int* rowptr = (int*)alloc((size_t)(N_ + 1) * 4);
    unsigned int* staging = (unsigned int*)alloc((size_t)E2 * 4);
    int* csr = (int*)alloc((size_t)E2 * 4);
    unsigned short* Hb = (unsigned short*)alloc((size_t)N_ * 128 * 2);
    float* G = (float*)alloc((size_t)N_ * 128 * 4);
    float* es = (float*)alloc((size_t)N_ * 4 * 4);
    float* ed = (float*)alloc((size_t)N_ * 4 * 4);
    float* h3 = (float*)alloc((size_t)N_ * 4);
    float* bn = (float*)alloc(512 * 4);

    // CSR build
    hipMemsetAsync(bCnt, 0, (size_t)NBMAX * 4, stream);
    k_hist<<<512, 256, 0, stream>>>(ei, bCnt, E_, N_);
    k_bscan<<<1, 256, 0, stream>>>(bCnt, bOff, bFill, rowptr, N_, E2);
    k_partition<<<(E2 + CHUNK - 1) / CHUNK, 256, 0, stream>>>(ei, bFill, staging, E_, N_);
    k_emit<<<NB, 256, 0, stream>>>(staging, bOff, rowptr, csr, N_);

    int gemmB = (N_ + 31) / 32;

    // ----- layer 1 -----
    k_gemm128<<<gemmB, 256, 0, stream>>>(x, W1, Hb, nullptr, nullptr, a1s, a1d, es, ed, N_);
    k_node_gat<<<N_, 128, 0, stream>>>(Hb, es, ed, rowptr, csr, b1, G, N_);
    hipMemsetAsync(bn, 0, 256 * 4, stream);
    k_bn_stats<<<512, 128, 0, stream>>>(G, bn, bn + 128, N_);
    k_bn_finalize<<<1, 128, 0, stream>>>(bn, bn + 128, g1, be1, bn + 256, bn + 384, N_);

    // ----- layer 2 (BN1+ReLU fused into GEMM X-load) -----
    k_gemm128<<<gemmB, 256, 0, stream>>>(G, W2, Hb, bn + 256, bn + 384, a2s, a2d, es, ed, N_);
    k_node_gat<<<N_, 128, 0, stream>>>(Hb, es, ed, rowptr, csr, b2, G, N_);
    hipMemsetAsync(bn, 0, 256 * 4, stream);
    k_bn_stats<<<512, 128, 0, stream>>>(G, bn, bn + 128, N_);
    k_bn_finalize<<<1, 128, 0, stream>>>(bn, bn + 128, g2, be2, bn + 256, bn + 384, N_);

    // ----- layer 3 (BN2+ReLU fused into dot) -----
    k_dot3<<<(N_ + 3) / 4, 256, 0, stream>>>(G, W3, bn + 256, bn + 384, h3, N_);
    k_gat3<<<N_, 64, 0, stream>>>(h3, a3s, a3d, b3, rowptr, csr, out, N_);
}

// Round 6
// 373.829 us; speedup vs baseline: 1.8356x; 1.0444x over previous
//
#include <hip/hip_runtime.h>
#include <hip/hip_fp16.h>
#include <math.h>

#define NEG_SLOPE 0.2f
#define NBMAX 256
#define CHUNK 4096
#define DCAP 16384

__device__ __forceinline__ float lrelu(float x) { return x > 0.f ? x : NEG_SLOPE * x; }

__device__ __forceinline__ unsigned short f2h(float f) {
    __half h = __float2half(f);
    return *(unsigned short*)&h;
}
__device__ __forceinline__ float h2f(unsigned short u) {
    __half h = *(__half*)&u;
    return __half2float(h);
}

// ---------------- CSR build: 2-level bucket counting sort ----------------
__global__ __launch_bounds__(256) void k_hist(const int* __restrict__ ei, int* __restrict__ bCnt,
                                              int E, int n) {
    __shared__ int lh[NBMAX];
    int NB = (n + 255) >> 8;
    for (int i = threadIdx.x; i < NB; i += 256) lh[i] = 0;
    __syncthreads();
    int E2 = E + n;
    for (int e = blockIdx.x * 256 + threadIdx.x; e < E2; e += gridDim.x * 256) {
        int d = (e < E) ? ei[E + e] : (e - E);
        atomicAdd(&lh[d >> 8], 1);
    }
    __syncthreads();
    for (int i = threadIdx.x; i < NB; i += 256)
        if (lh[i]) atomicAdd(&bCnt[i], lh[i]);
}

__global__ __launch_bounds__(256) void k_bscan(const int* __restrict__ bCnt, int* __restrict__ bOff,
                                               int* __restrict__ bFill, int* __restrict__ rowptr,
                                               int n, int E2) {
    int NB = (n + 255) >> 8;
    int tid = threadIdx.x, lane = tid & 63, wid = tid >> 6;
    int v = (tid < NB) ? bCnt[tid] : 0;
    int s = v;
    #pragma unroll
    for (int off = 1; off < 64; off <<= 1) {
        int t = __shfl_up(s, off);
        if (lane >= off) s += t;
    }
    __shared__ int ws[4];
    if (lane == 63) ws[wid] = s;
    __syncthreads();
    if (tid == 0) {
        int c = 0;
        #pragma unroll
        for (int i = 0; i < 4; ++i) { int t = ws[i]; ws[i] = c; c += t; }
    }
    __syncthreads();
    s += ws[wid];
    int excl = s - v;
    if (tid < NB) { bOff[tid] = excl; bFill[tid] = excl; }
    if (tid == NB - 1) bOff[NB] = excl + v;
    if (tid == 0) rowptr[n] = E2;
}

__global__ __launch_bounds__(256) void k_partition(const int* __restrict__ ei, int* __restrict__ bFill,
                                                   unsigned int* __restrict__ staging, int E, int n) {
    __shared__ int lh[NBMAX];
    __shared__ int lbase[NBMAX];
    int NB = (n + 255) >> 8;
    int E2 = E + n;
    int beg = blockIdx.x * CHUNK;
    int end = min(beg + CHUNK, E2);
    for (int i = threadIdx.x; i < NB; i += 256) lh[i] = 0;
    __syncthreads();
    for (int e = beg + threadIdx.x; e < end; e += 256) {
        int d = (e < E) ? ei[E + e] : (e - E);
        atomicAdd(&lh[d >> 8], 1);
    }
    __syncthreads();
    for (int i = threadIdx.x; i < NB; i += 256) {
        int c = lh[i];
        lbase[i] = c ? atomicAdd(&bFill[i], c) : 0;
        lh[i] = 0;
    }
    __syncthreads();
    for (int e = beg + threadIdx.x; e < end; e += 256) {
        int s, d;
        if (e < E) { s = ei[e]; d = ei[E + e]; } else { s = d = e - E; }
        int b = d >> 8;
        int r = atomicAdd(&lh[b], 1);
        staging[lbase[b] + r] = ((unsigned)s << 8) | (unsigned)(d & 255);
    }
}

__global__ __launch_bounds__(512) void k_emit(const unsigned int* __restrict__ staging,
                                              const int* __restrict__ bOff, int* __restrict__ rowptr,
                                              int* __restrict__ csr, int n) {
    __shared__ int lcnt[NBMAX];
    __shared__ int lscan[NBMAX];
    __shared__ int ws[4];
    __shared__ int sorted[DCAP];  // 64 KB
    int b = blockIdx.x;
    int gbase = b << 8;
    int beg = bOff[b], end = bOff[b + 1], m = end - beg;
    int tid = threadIdx.x, lane = tid & 63, wid = tid >> 6;

    if (tid < 256) lcnt[tid] = 0;
    __syncthreads();
    for (int j = tid; j < m; j += 512) atomicAdd(&lcnt[staging[beg + j] & 255], 1);
    __syncthreads();
    int v = 0, s = 0;
    if (tid < 256) {
        v = lcnt[tid];
        s = v;
        #pragma unroll
        for (int off = 1; off < 64; off <<= 1) {
            int t = __shfl_up(s, off);
            if (lane >= off) s += t;
        }
        if (lane == 63) ws[wid] = s;
    }
    __syncthreads();
    if (tid == 0) {
        int c = 0;
        #pragma unroll
        for (int i = 0; i < 4; ++i) { int t = ws[i]; ws[i] = c; c += t; }
    }
    __syncthreads();
    if (tid < 256) {
        int excl = s + ws[wid] - v;
        lscan[tid] = excl;
        lcnt[tid] = 0;
        if (gbase + tid < n) rowptr[gbase + tid] = beg + excl;
    }
    __syncthreads();

    if (m <= DCAP) {
        for (int j = tid; j < m; j += 512) {
            unsigned e = staging[beg + j];
            int ld = e & 255;
            int src = e >> 8;
            int r = atomicAdd(&lcnt[ld], 1);
            sorted[lscan[ld] + r] = src;
        }
        __syncthreads();
        for (int j = tid; j < m; j += 512) csr[beg + j] = sorted[j];
    } else {
        for (int j = tid; j < m; j += 512) {
            unsigned e = staging[beg + j];
            int ld = e & 255;
            int src = e >> 8;
            int r = atomicAdd(&lcnt[ld], 1);
            csr[beg + lscan[ld] + r] = src;
        }
    }
}

// ---------------- GEMM: H(f16) = relu(X*scale+shift) @ W, fused es/ed epilogue ----------------
__global__ __launch_bounds__(256) void k_gemm128(const float* __restrict__ X, const float* __restrict__ W,
                                                 unsigned short* __restrict__ Hout,
                                                 const float* __restrict__ scale, const float* __restrict__ shift,
                                                 const float* __restrict__ as_f, const float* __restrict__ ad_f,
                                                 float* __restrict__ es, float* __restrict__ ed, int n) {
    __shared__ float Wl[64 * 128];  // 32 KB
    __shared__ float Xl[64 * 32];   // 8 KB, swizzled
    int tid = threadIdx.x;
    int row0 = blockIdx.x * 32;
    int cg = tid & 31, ng = tid >> 5;
    int c0 = cg * 4, r0 = ng * 4;
    float acc[4][4] = {{0.f}};
    for (int kb = 0; kb < 128; kb += 64) {
        const float4* Wg = (const float4*)(W + (size_t)kb * 128);
        float4* Wl4 = (float4*)Wl;
        #pragma unroll
        for (int j = 0; j < 8; ++j) Wl4[tid + j * 256] = Wg[tid + j * 256];
        #pragma unroll
        for (int j = 0; j < 2; ++j) {
            int idx = tid + j * 256;
            int r = idx >> 4;
            int k4 = idx & 15;
            float4 v = make_float4(0.f, 0.f, 0.f, 0.f);
            if (row0 + r < n) v = ((const float4*)(X + (size_t)(row0 + r) * 128 + kb))[k4];
            if (scale) {
                int kc = kb + k4 * 4;
                float4 sc = *(const float4*)&scale[kc];
                float4 sh = *(const float4*)&shift[kc];
                v.x = fmaxf(v.x * sc.x + sh.x, 0.f);
                v.y = fmaxf(v.y * sc.y + sh.y, 0.f);
                v.z = fmaxf(v.z * sc.z + sh.z, 0.f);
                v.w = fmaxf(v.w * sc.w + sh.w, 0.f);
            }
            int k = k4 * 4;
            Xl[(k + 0) * 32 + (r ^ ((k + 0) & 31))] = v.x;
            Xl[(k + 1) * 32 + (r ^ ((k + 1) & 31))] = v.y;
            Xl[(k + 2) * 32 + (r ^ ((k + 2) & 31))] = v.z;
            Xl[(k + 3) * 32 + (r ^ ((k + 3) & 31))] = v.w;
        }
        __syncthreads();
        #pragma unroll
        for (int k = 0; k < 64; ++k) {
            float4 wv = *(const float4*)&Wl[k * 128 + c0];
            float x0 = Xl[k * 32 + ((r0 + 0) ^ (k & 31))];
            float x1 = Xl[k * 32 + ((r0 + 1) ^ (k & 31))];
            float x2 = Xl[k * 32 + ((r0 + 2) ^ (k & 31))];
            float x3 = Xl[k * 32 + ((r0 + 3) ^ (k & 31))];
            acc[0][0] += x0 * wv.x; acc[0][1] += x0 * wv.y; acc[0][2] += x0 * wv.z; acc[0][3] += x0 * wv.w;
            acc[1][0] += x1 * wv.x; acc[1][1] += x1 * wv.y; acc[1][2] += x1 * wv.z; acc[1][3] += x1 * wv.w;
            acc[2][0] += x2 * wv.x; acc[2][1] += x2 * wv.y; acc[2][2] += x2 * wv.z; acc[2][3] += x2 * wv.w;
            acc[3][0] += x3 * wv.x; acc[3][1] += x3 * wv.y; acc[3][2] += x3 * wv.z; acc[3][3] += x3 * wv.w;
        }
        __syncthreads();
    }
    #pragma unroll
    for (int i = 0; i < 4; ++i) {
        int r = row0 + r0 + i;
        if (r < n) {
            ushort4 o;
            o.x = f2h(acc[i][0]);
            o.y = f2h(acc[i][1]);
            o.z = f2h(acc[i][2]);
            o.w = f2h(acc[i][3]);
            *(ushort4*)&Hout[(size_t)r * 128 + c0] = o;
        }
    }
    // fused attention-score epilogue (fp32 acc -> exact es/ed)
    float4 asv = *(const float4*)&as_f[c0];
    float4 adv = *(const float4*)&ad_f[c0];
    float ps[4], pd[4];
    #pragma unroll
    for (int i = 0; i < 4; ++i) {
        ps[i] = acc[i][0] * asv.x + acc[i][1] * asv.y + acc[i][2] * asv.z + acc[i][3] * asv.w;
        pd[i] = acc[i][0] * adv.x + acc[i][1] * adv.y + acc[i][2] * adv.z + acc[i][3] * adv.w;
    }
    #pragma unroll
    for (int off = 1; off <= 4; off <<= 1) {
        #pragma unroll
        for (int i = 0; i < 4; ++i) {
            ps[i] += __shfl_xor(ps[i], off);
            pd[i] += __shfl_xor(pd[i], off);
        }
    }
    if ((cg & 7) == 0) {
        int hh = cg >> 3;
        #pragma unroll
        for (int i = 0; i < 4; ++i) {
            int r = row0 + r0 + i;
            if (r < n) {
                es[(size_t)r * 4 + hh] = ps[i];
                ed[(size_t)r * 4 + hh] = pd[i];
            }
        }
    }
}

// ---------------- per-node GAT: node-per-wave, f16 H gather, barrier-free ----------------
// 256 thr = 4 waves = 4 independent nodes. Wave: 32 channel-groups x 2 edge
// slots. No LDS, no __syncthreads; slot combine = one shfl_xor(32).
__global__ __launch_bounds__(256) void k_node_gat(
    const unsigned short* __restrict__ Hf, const float* __restrict__ es, const float* __restrict__ ed,
    const int* __restrict__ ptr, const int* __restrict__ csr,
    const float* __restrict__ bias, float* __restrict__ out, int n) {
    int nd = blockIdx.x * 4 + (threadIdx.x >> 6);
    if (nd >= n) return;
    int lane = threadIdx.x & 63;
    int cg = lane & 31;    // channel group (4 ch)
    int slot = lane >> 5;  // 0..1
    int hh = cg >> 3;      // head
    int beg = ptr[nd], deg = ptr[nd + 1] - beg;

    float edn = ed[(size_t)nd * 4 + hh] - 16.f;
    const ushort4* H2 = (const ushort4*)Hf;  // row stride = 32 ushort4

    float4 acc = make_float4(0.f, 0.f, 0.f, 0.f);
    float den = 0.f;

    int i = slot;
    for (; i + 2 < deg; i += 4) {
        int s0 = csr[beg + i];
        int s1 = csr[beg + i + 2];
        float e0 = es[(size_t)s0 * 4 + hh];
        float e1 = es[(size_t)s1 * 4 + hh];
        ushort4 p0 = H2[(size_t)s0 * 32 + cg];
        ushort4 p1 = H2[(size_t)s1 * 32 + cg];
        float w0 = __expf(lrelu(e0 + edn - (edn - edn)) + edn >= e0 + edn ? 0.f : 0.f);  // placeholder avoided
        w0 = __expf(lrelu(e0 + (edn + 16.f)) - 16.f);
        float w1 = __expf(lrelu(e1 + (edn + 16.f)) - 16.f);
        den += w0 + w1;
        acc.x += w0 * h2f(p0.x) + w1 * h2f(p1.x);
        acc.y += w0 * h2f(p0.y) + w1 * h2f(p1.y);
        acc.z += w0 * h2f(p0.z) + w1 * h2f(p1.z);
        acc.w += w0 * h2f(p0.w) + w1 * h2f(p1.w);
    }
    if (i < deg) {
        int s0 = csr[beg + i];
        float e0 = es[(size_t)s0 * 4 + hh];
        ushort4 p0 = H2[(size_t)s0 * 32 + cg];
        float w0 = __expf(lrelu(e0 + (edn + 16.f)) - 16.f);
        den += w0;
        acc.x += w0 * h2f(p0.x);
        acc.y += w0 * h2f(p0.y);
        acc.z += w0 * h2f(p0.z);
        acc.w += w0 * h2f(p0.w);
    }

    // combine the two slots: lanes l and l+32
    acc.x += __shfl_xor(acc.x, 32);
    acc.y += __shfl_xor(acc.y, 32);
    acc.z += __shfl_xor(acc.z, 32);
    acc.w += __shfl_xor(acc.w, 32);
    den += __shfl_xor(den, 32);

    if (lane < 32) {
        float inv = 1.f / (den + 1e-16f);
        float4 bv = *(const float4*)&bias[cg * 4];
        float4 o = make_float4(acc.x * inv + bv.x, acc.y * inv + bv.y,
                               acc.z * inv + bv.z, acc.w * inv + bv.w);
        *(float4*)&out[(size_t)nd * 128 + cg * 4] = o;
    }
}

// ---------------- batch norm stats ----------------
__global__ __launch_bounds__(128) void k_bn_stats(const float* __restrict__ G, float* __restrict__ sum,
                                                  float* __restrict__ sumsq, int n) {
    int c = threadIdx.x;
    float s = 0.f, s2 = 0.f;
    for (int r = blockIdx.x; r < n; r += gridDim.x) {
        float v = G[(size_t)r * 128 + c];
        s += v;
        s2 += v * v;
    }
    atomicAdd(&sum[c], s);
    atomicAdd(&sumsq[c], s2);
}

__global__ void k_bn_finalize(const float* __restrict__ sum, const float* __restrict__ sumsq,
                              const float* __restrict__ g, const float* __restrict__ be,
                              float* __restrict__ scale, float* __restrict__ shift, int n) {
    int c = threadIdx.x;  // 128
    float mean = sum[c] / (float)n;
    float var = sumsq[c] / (float)n - mean * mean;
    float sc = g[c] * rsqrtf(var + 1e-5f);
    scale[c] = sc;
    shift[c] = be[c] - mean * sc;
}

// ---------------- layer 3 (BN+ReLU fused into dot) ----------------
__global__ __launch_bounds__(256) void k_dot3(const float* __restrict__ F, const float* __restrict__ W3,
                                              const float* __restrict__ scale, const float* __restrict__ shift,
                                              float* __restrict__ h3, int n) {
    int wid = threadIdx.x >> 6, lane = threadIdx.x & 63;
    int nd = blockIdx.x * 4 + wid;
    if (nd >= n) return;
    const float* row = F + (size_t)nd * 128;
    float v0 = fmaxf(row[lane] * scale[lane] + shift[lane], 0.f);
    float v1 = fmaxf(row[lane + 64] * scale[lane + 64] + shift[lane + 64], 0.f);
    float v = v0 * W3[lane] + v1 * W3[lane + 64];
    #pragma unroll
    for (int off = 32; off > 0; off >>= 1) v += __shfl_xor(v, off);
    if (lane == 0) h3[nd] = v;
}

__global__ __launch_bounds__(64) void k_gat3(const float* __restrict__ h3, const float* __restrict__ a3s,
                                             const float* __restrict__ a3d, const float* __restrict__ b3,
                                             const int* __restrict__ ptr, const int* __restrict__ csr,
                                             float* __restrict__ out, int n) {
    int nd = blockIdx.x;
    if (nd >= n) return;
    int lane = threadIdx.x;
    int beg = ptr[nd], deg = ptr[nd + 1] - beg;
    float As = a3s[0], Ad = a3d[0], B = b3[0];
    float hd = h3[nd] * Ad;
    float den = 0.f, num = 0.f;
    for (int i = lane; i < deg; i += 64) {
        float hs = h3[csr[beg + i]];
        float a = lrelu(hs * As + hd);
        float ex = __expf(a - 16.f);
        den += ex;
        num += ex * hs;
    }
    #pragma unroll
    for (int off = 32; off > 0; off >>= 1) {
        den += __shfl_xor(den, off);
        num += __shfl_xor(num, off);
    }
    if (lane == 0) out[nd] = fmaxf(num / (den + 1e-16f) + B, 0.f);
}

// ---------------- launch ----------------
extern "C" void kernel_launch(void* const* d_in, const int* in_sizes, int n_in,
                              void* d_out, int out_size, void* d_ws, size_t ws_size,
                              hipStream_t stream) {
    const int N_ = in_sizes[0] / 128;
    const int E_ = in_sizes[1] / 2;
    const int E2 = E_ + N_;
    const int NB = (N_ + 255) >> 8;

    const float* x = (const float*)d_in[0];
    const int* ei = (const int*)d_in[1];
    const float* W1 = (const float*)d_in[2];
    const float* a1s = (const float*)d_in[3];
    const float* a1d = (const float*)d_in[4];
    const float* b1 = (const float*)d_in[5];
    const float* g1 = (const float*)d_in[6];
    const float* be1 = (const float*)d_in[7];
    const float* W2 = (const float*)d_in[8];
    const float* a2s = (const float*)d_in[9];
    const float* a2d = (const float*)d_in[10];
    const float* b2 = (const float*)d_in[11];
    const float* g2 = (const float*)d_in[12];
    const float* be2 = (const float*)d_in[13];
    const float* W3 = (const float*)d_in[14];
    const float* a3s = (const float*)d_in[15];
    const float* a3d = (const float*)d_in[16];
    const float* b3 = (const float*)d_in[17];
    float* out = (float*)d_out;

    char* p = (char*)d_ws;
    auto alloc = [&](size_t bytes) {
        void* r = (void*)p;
        p += (bytes + 255) & ~(size_t)255;
        return r;
    };
    int* bCnt = (int*)alloc((size_t)NBMAX * 4);
    int* bOff = (int*)alloc((size_t)(NBMAX + 1) * 4);
    int* bFill = (int*)alloc((size_t)NBMAX * 4);
    int* rowptr = (int*)alloc((size_t)(N_ + 1) * 4);
    unsigned int* staging = (unsigned int*)alloc((size_t)E2 * 4);
    int* csr = (int*)alloc((size_t)E2 * 4);
    unsigned short* Hb = (unsigned short*)alloc((size_t)N_ * 128 * 2);
    float* G = (float*)alloc((size_t)N_ * 128 * 4);
    float* es = (float*)alloc((size_t)N_ * 4 * 4);
    float* ed = (float*)alloc((size_t)N_ * 4 * 4);
    float* h3 = (float*)alloc((size_t)N_ * 4);
    float* bn = (float*)alloc(512 * 4);

    // CSR build
    hipMemsetAsync(bCnt, 0, (size_t)NBMAX * 4, stream);
    k_hist<<<512, 256, 0, stream>>>(ei, bCnt, E_, N_);
    k_bscan<<<1, 256, 0, stream>>>(bCnt, bOff, bFill, rowptr, N_, E2);
    k_partition<<<(E2 + CHUNK - 1) / CHUNK, 256, 0, stream>>>(ei, bFill, staging, E_, N_);
    k_emit<<<NB, 512, 0, stream>>>(staging, bOff, rowptr, csr, N_);

    int gemmB = (N_ + 31) / 32;
    int gatB = (N_ + 3) / 4;

    // ----- layer 1 -----
    k_gemm128<<<gemmB, 256, 0, stream>>>(x, W1, Hb, nullptr, nullptr, a1s, a1d, es, ed, N_);
    k_node_gat<<<gatB, 256, 0, stream>>>(Hb, es, ed, rowptr, csr, b1, G, N_);
    hipMemsetAsync(bn, 0, 256 * 4, stream);
    k_bn_stats<<<512, 128, 0, stream>>>(G, bn, bn + 128, N_);
    k_bn_finalize<<<1, 128, 0, stream>>>(bn, bn + 128, g1, be1, bn + 256, bn + 384, N_);

    // ----- layer 2 (BN1+ReLU fused into GEMM X-load) -----
    k_gemm128<<<gemmB, 256, 0, stream>>>(G, W2, Hb, bn + 256, bn + 384, a2s, a2d, es, ed, N_);
    k_node_gat<<<gatB, 256, 0, stream>>>(Hb, es, ed, rowptr, csr, b2, G, N_);
    hipMemsetAsync(bn, 0, 256 * 4, stream);
    k_bn_stats<<<512, 128, 0, stream>>>(G, bn, bn + 128, N_);
    k_bn_finalize<<<1, 128, 0, stream>>>(bn, bn + 128, g2, be2, bn + 256, bn + 384, N_);

    // ----- layer 3 (BN2+ReLU fused into dot) -----
    k_dot3<<<(N_ + 3) / 4, 256, 0, stream>>>(G, W3, bn + 256, bn + 384, h3, N_);
    k_gat3<<<N_, 64, 0, stream>>>(h3, a3s, a3d, b3, rowptr, csr, out, N_);
}